// Round 2
// baseline (41568.399 us; speedup 1.0000x reference)
//
#include <hip/hip_runtime.h>
#include <hip/hip_bf16.h>
#include <hip/hip_cooperative_groups.h>

namespace cgrp = cooperative_groups;

// ============================================================================
// BilateralGenerator: 3-layer coupled LSTM, B=128 T=512 H=512 ND=128 LD=128.
//
// Round 8: r7 data fits T = C/waves + O with O ~= 13.6us/tick fixed overhead
// (launch gap + dispatch ramp/drain + cold-cache restart, x515 launches).
// Compute is ~1.5-3us/tick. This round removes the 515 launches entirely:
//  - ONE persistent cooperative kernel, internal loop over 515 ticks,
//    grid.sync() per tick. All cross-tick deps are "written last tick"
//    (parity-double-buffered h, c RMW by the same block), so 1 barrier/tick
//    is exact.
//  - __threadfence() (device-scope release) before grid.sync() for cross-XCD
//    h/c visibility (per-XCD L2 non-coherent).
//  - 194 blocks x 512 thr, 128KB LDS -> 1 block/CU, co-resident on 256 CUs.
//  - Tick body byte-identical to r7 (waves 0-3 x-path K-quarters, 4-7 h-path,
//    8-way LDS partial exchange, fused activation epilogue).
// Math identical to r2/r5/r6/r7 (split-precision bf16 hi/lo GEMMs).
// ============================================================================

typedef unsigned short ushort_t;

using frag_ab = __attribute__((ext_vector_type(8))) short;  // 8 bf16
using frag_cd = __attribute__((ext_vector_type(4))) float;  // 4 fp32

#define B_   128
#define T_   512
#define ND_  128
#define H_   512
#define G_   2048   // 4*H
#define LD_  128

// ---- workspace layout (ushort element offsets into bf16 region) ----
#define OFF_WHH   0u          // Wh hi: 3 x 512*2048
#define OFF_WHL   3145728u    // Wh lo
#define OFF_WXH   6291456u    // Wx hi: Wx0 (128*2048) then Wxr[0], Wxr[1]
#define OFF_WXL   8650752u    // Wx lo
#define OFF_WCH   11010048u   // Wc hi: 3 x 512*2048
#define OFF_WCL   14155776u   // Wc lo
#define OFF_WOUT  17301504u   // Wout hi: 512*128
#define OFF_HCH   17367040u   // h_coupled hi: 3 x 128*512
#define OFF_HCL   17563648u   // h_coupled lo
#define OFF_HBH   17760256u   // h buf hi: 3 layers x 2 parity x 128*512
#define OFF_HBL   18153472u   // h buf lo
#define OFF_SCR   18546688u   // scratch (Wout lo, unused): 65536
#define USH_BYTES 37224448u   // 18612224 ushorts * 2
// ---- fp32 region (float element offsets from USH_BYTES) ----
#define FOFF_C     0u         // c state: 3 x 128*512
#define FOFF_CTERM 196608u    // Cterm: 3 x 128*2048

__device__ inline float sig_(float x)  { return 1.0f / (1.0f + __expf(-x)); }
__device__ inline float tanh_(float x) { return 2.0f / (1.0f + __expf(-2.0f * x)) - 1.0f; }

__device__ inline ushort_t f2b(float f) {
    __hip_bfloat16 h = __float2bfloat16(f);           // RNE
    return __builtin_bit_cast(unsigned short, h);
}
__device__ inline float b2f(ushort_t u) {
    unsigned int v = ((unsigned int)u) << 16;
    return __builtin_bit_cast(float, v);
}

// ---------------------------------------------------------------------------
// Weight swizzle + hi/lo split (round-2 verified).
// ---------------------------------------------------------------------------
__global__ void swz_kernel(const float* __restrict__ src,
                           ushort_t* __restrict__ dhi, ushort_t* __restrict__ dlo,
                           int K, int N) {
    int tid = blockIdx.x * 256 + threadIdx.x;
    int total = (K >> 5) * (N >> 4) * 64;
    if (tid >= total) return;
    int lane = tid & 63;
    int rest = tid >> 6;
    int NF = N >> 4;
    int nf = rest % NF;
    int kb = rest / NF;
    int kbase = kb * 32 + (lane >> 4) * 8;
    int n = nf * 16 + (lane & 15);
    union { ushort_t u[8]; uint4 v; } thi, tlo;
#pragma unroll
    for (int j = 0; j < 8; ++j) {
        float v = src[(size_t)(kbase + j) * N + n];
        ushort_t hi = f2b(v);
        thi.u[j] = hi;
        tlo.u[j] = f2b(v - b2f(hi));
    }
    *(uint4*)(dhi + (size_t)tid * 8) = thi.v;
    *(uint4*)(dlo + (size_t)tid * 8) = tlo.v;
}

__global__ void cvt_kernel(const float* __restrict__ src,
                           ushort_t* __restrict__ dhi, ushort_t* __restrict__ dlo, int n) {
    int i = blockIdx.x * 256 + threadIdx.x;
    if (i >= n) return;
    float v = src[i];
    ushort_t hi = f2b(v);
    dhi[i] = hi;
    dlo[i] = f2b(v - b2f(hi));
}

// ---------------------------------------------------------------------------
// Split-precision [16x64]-per-wave GEMM (round-2 verified) for cterm only.
// ---------------------------------------------------------------------------
__device__ inline void mfma_seg3(const ushort_t* __restrict__ Ah,
                                 const ushort_t* __restrict__ Al,
                                 const ushort_t* __restrict__ Bh,
                                 const ushort_t* __restrict__ Bl,
                                 int rowA, int cg, int nkb, frag_cd acc[4]) {
    int lane = threadIdx.x & 63;
    int koff = (lane >> 4) * 8;
#pragma unroll 2
    for (int kb = 0; kb < nkb; ++kb) {
        frag_ab ah = *(const frag_ab*)(Ah + (size_t)rowA * H_ + kb * 32 + koff);
        frag_ab al = *(const frag_ab*)(Al + (size_t)rowA * H_ + kb * 32 + koff);
#pragma unroll
        for (int q = 0; q < 4; ++q) {
            size_t bo = ((size_t)(kb * 128 + q * 32 + cg) * 64 + lane) * 8;
            frag_ab bh = *(const frag_ab*)(Bh + bo);
            frag_ab bl = *(const frag_ab*)(Bl + bo);
            acc[q] = __builtin_amdgcn_mfma_f32_16x16x32_bf16(ah, bh, acc[q], 0, 0, 0);
            acc[q] = __builtin_amdgcn_mfma_f32_16x16x32_bf16(ah, bl, acc[q], 0, 0, 0);
            acc[q] = __builtin_amdgcn_mfma_f32_16x16x32_bf16(al, bh, acc[q], 0, 0, 0);
        }
    }
}

__global__ __launch_bounds__(256) void cterm_kernel(char* __restrict__ ws,
                                                    const float* __restrict__ bias) {
    ushort_t* wsU = (ushort_t*)ws;
    float* wsF = (float*)(ws + USH_BYTES);
    int lane = threadIdx.x & 63, w = threadIdx.x >> 6;
    int bid = blockIdx.x;
    int layer = bid >> 6;
    int sub = bid & 63;
    int rg = sub >> 5, cg = sub & 31;
    int m = lane & 15, kq = lane >> 4;
    int r0 = rg * 64 + w * 16;
    int rowA = r0 + m;
    frag_cd acc[4] = {};
    mfma_seg3(wsU + OFF_HCH + layer * 65536, wsU + OFF_HCL + layer * 65536,
              wsU + OFF_WCH + (size_t)layer * 1048576, wsU + OFF_WCL + (size_t)layer * 1048576,
              rowA, cg, 16, acc);
    float* ct = wsF + FOFF_CTERM + (size_t)layer * 262144;
#pragma unroll
    for (int reg = 0; reg < 4; ++reg) {
        int row = r0 + kq * 4 + reg;
#pragma unroll
        for (int q = 0; q < 4; ++q) {
            int gcol = q * 512 + cg * 16 + m;
            ct[(size_t)row * G_ + gcol] = acc[q][reg] + bias[layer * G_ + gcol];
        }
    }
}

// ---------------------------------------------------------------------------
// Split-precision [64 rows x 64 gcols]-per-wave K-chunk segment: 4 rowtiles,
// B frags reused 4x from registers, kb in [kb0, kb0+nkb). Static acc indices.
// ---------------------------------------------------------------------------
__device__ inline void seg_accum64k(const ushort_t* __restrict__ Ah,
                                    const ushort_t* __restrict__ Al,
                                    const ushort_t* __restrict__ Bh,
                                    const ushort_t* __restrict__ Bl,
                                    int r0, int cg, int kb0, int nkb, frag_cd acc[4][4]) {
    int lane = threadIdx.x & 63;
    int m = lane & 15;
    int koff = (lane >> 4) * 8;
#pragma unroll 2
    for (int kb = kb0; kb < kb0 + nkb; ++kb) {
        frag_ab ah[4], al[4];
#pragma unroll
        for (int rt = 0; rt < 4; ++rt) {
            size_t ao = (size_t)(r0 + rt * 16 + m) * H_ + kb * 32 + koff;
            ah[rt] = *(const frag_ab*)(Ah + ao);
            al[rt] = *(const frag_ab*)(Al + ao);
        }
#pragma unroll
        for (int q = 0; q < 4; ++q) {
            size_t bo = ((size_t)(kb * 128 + q * 32 + cg) * 64 + lane) * 8;
            frag_ab bh = *(const frag_ab*)(Bh + bo);
            frag_ab bl = *(const frag_ab*)(Bl + bo);
#pragma unroll
            for (int rt = 0; rt < 4; ++rt) {
                acc[rt][q] = __builtin_amdgcn_mfma_f32_16x16x32_bf16(ah[rt], bh, acc[rt][q], 0, 0, 0);
                acc[rt][q] = __builtin_amdgcn_mfma_f32_16x16x32_bf16(ah[rt], bl, acc[rt][q], 0, 0, 0);
                acc[rt][q] = __builtin_amdgcn_mfma_f32_16x16x32_bf16(al[rt], bh, acc[rt][q], 0, 0, 0);
            }
        }
    }
}

// ---------------------------------------------------------------------------
// Persistent pipeline: 194 blocks x 512 threads (8 waves), 515 internal ticks,
// grid.sync() per tick. bid < 192: cell blocks, bid = rg64*96 + (layer*32+cg).
// Block computes the [64r x 64gc] tile: waves 0-3 = x-path K quarters, waves
// 4-7 = h-path K quarters; 8-way LDS partial-sum (128 KB) + epilogue.
// bid 192/193: out-proj, 8 waves each = (16-row group, col-half).
// ---------------------------------------------------------------------------
__global__ __launch_bounds__(512, 2) void tick_persist(const float* __restrict__ noise,
                                                       char* __restrict__ ws,
                                                       float* __restrict__ out,
                                                       const float* __restrict__ bout) {
    cgrp::grid_group grid = cgrp::this_grid();
    __shared__ float ex[8][4096];   // 128 KB: per-wave [64r x 64gc] partials

    ushort_t* wsU = (ushort_t*)ws;
    float* wsF = (float*)(ws + USH_BYTES);
    const int lane = threadIdx.x & 63;
    const int w = threadIdx.x >> 6;       // wave id 0..7
    const int bid = blockIdx.x;
    const int m = lane & 15, kq = lane >> 4;
    const int koff = kq * 8;

    // ---- tick-invariant block identity ----
    const int rg64 = (bid < 192) ? (bid / 96) : 0;   // 0..1: 64-row group
    const int u    = (bid < 192) ? (bid % 96) : 0;   // XCD = u % 8
    const int layer = u >> 5;
    const int cg    = u & 31;
    const int r0    = rg64 * 64;
    const int owid = (bid - 192) * 8 + w;            // out-proj: 0..15
    const int org  = owid >> 1;                      // 8 rowgroups of 16
    const int och  = owid & 1;                       // 2 col halves of 64
    const int r0o  = org * 16;

    for (int tick = 0; tick < 515; ++tick) {
        if (bid < 192) {
            int s = tick - layer;
            if (s >= 0 && s < T_) {
                frag_cd acc[4][4] = {};

                if (w < 4) {
                    // ---- x-path K-quarter (layer0: noise K=128 -> kb = w)
                    if (layer == 0) {
                        const ushort_t* Bh = wsU + OFF_WXH;
                        const ushort_t* Bl = wsU + OFF_WXL;
                        int kb = w;
                        frag_ab ah[4], al[4];
#pragma unroll
                        for (int rt = 0; rt < 4; ++rt) {
                            const float* np = noise +
                                ((size_t)(r0 + rt * 16 + m) * T_ + s) * ND_ + kb * 32 + koff;
                            float4 f0 = *(const float4*)np;
                            float4 f1 = *(const float4*)(np + 4);
                            float xf[8] = {f0.x, f0.y, f0.z, f0.w, f1.x, f1.y, f1.z, f1.w};
#pragma unroll
                            for (int j = 0; j < 8; ++j) {
                                ushort_t hi = f2b(xf[j]);
                                ah[rt][j] = (short)hi;
                                al[rt][j] = (short)f2b(xf[j] - b2f(hi));
                            }
                        }
#pragma unroll
                        for (int q = 0; q < 4; ++q) {
                            size_t bo = ((size_t)(kb * 128 + q * 32 + cg) * 64 + lane) * 8;
                            frag_ab bh = *(const frag_ab*)(Bh + bo);
                            frag_ab bl = *(const frag_ab*)(Bl + bo);
#pragma unroll
                            for (int rt = 0; rt < 4; ++rt) {
                                acc[rt][q] = __builtin_amdgcn_mfma_f32_16x16x32_bf16(ah[rt], bh, acc[rt][q], 0, 0, 0);
                                acc[rt][q] = __builtin_amdgcn_mfma_f32_16x16x32_bf16(ah[rt], bl, acc[rt][q], 0, 0, 0);
                                acc[rt][q] = __builtin_amdgcn_mfma_f32_16x16x32_bf16(al[rt], bh, acc[rt][q], 0, 0, 0);
                            }
                        }
                    } else {
                        unsigned hb = (unsigned)((layer - 1) * 2 + (s & 1)) * 65536u;
                        seg_accum64k(wsU + OFF_HBH + hb, wsU + OFF_HBL + hb,
                                     wsU + OFF_WXH + 262144u + (size_t)(layer - 1) * 1048576,
                                     wsU + OFF_WXL + 262144u + (size_t)(layer - 1) * 1048576,
                                     r0, cg, w * 4, 4, acc);
                    }
                } else if (s > 0) {
                    // ---- h-path K-quarter (skip at s==0)
                    unsigned hb = (unsigned)(layer * 2 + ((s - 1) & 1)) * 65536u;
                    seg_accum64k(wsU + OFF_HBH + hb, wsU + OFF_HBL + hb,
                                 wsU + OFF_WHH + (size_t)layer * 1048576,
                                 wsU + OFF_WHL + (size_t)layer * 1048576,
                                 r0, cg, (w - 4) * 4, 4, acc);
                }

                // ---- write this wave's partial tile to LDS (static acc indices)
                {
                    float* eb = &ex[w][0];
#pragma unroll
                    for (int rt = 0; rt < 4; ++rt)
#pragma unroll
                        for (int q = 0; q < 4; ++q)
#pragma unroll
                            for (int reg = 0; reg < 4; ++reg)
                                eb[(rt * 16 + kq * 4 + reg) * 64 + q * 16 + m] = acc[rt][q][reg];
                }
                __syncthreads();

                // ---- combine 8 partials + activation epilogue: 2 elements/thread
                const float* ct = wsF + FOFF_CTERM + (size_t)layer * 262144;
                float* cst = wsF + FOFF_C + layer * 65536;
                ushort_t* hhi = wsU + OFF_HBH + (layer * 2 + (s & 1)) * 65536;
                ushort_t* hlo = wsU + OFF_HBL + (layer * 2 + (s & 1)) * 65536;
                int tid = threadIdx.x;
#pragma unroll
                for (int ee = 0; ee < 2; ++ee) {
                    int e = tid + ee * 512;     // 0..1023
                    int row = e >> 4;           // 0..63 within tile
                    int hcol = e & 15;
                    int grow = r0 + row;
                    int hc = cg * 16 + hcol;
                    int rb = row * 64 + hcol;
                    float gi = 0.0f, gf = 0.0f, gg = 0.0f, go = 0.0f;
#pragma unroll
                    for (int wv = 0; wv < 8; ++wv) {
                        gi += ex[wv][rb +  0];
                        gf += ex[wv][rb + 16];
                        gg += ex[wv][rb + 32];
                        go += ex[wv][rb + 48];
                    }
                    const float* cr = ct + (size_t)grow * G_ + hc;
                    gi += cr[0]; gf += cr[512]; gg += cr[1024]; go += cr[1536];
                    float cp = (s > 0) ? cst[grow * H_ + hc] : 0.0f;
                    float cn = sig_(gf) * cp + sig_(gi) * tanh_(gg);
                    float hn = sig_(go) * tanh_(cn);
                    cst[grow * H_ + hc] = cn;
                    ushort_t hi = f2b(hn);
                    hhi[grow * H_ + hc] = hi;
                    hlo[grow * H_ + hc] = f2b(hn - b2f(hi));
                    if (s == T_ - 1)   // h_fin, fp32, no bf16 quantization
                        out[8388608u + (size_t)layer * 65536 + grow * H_ + hc] = hn;
                }
            }
        } else {
            // ---- output projection: out[:, sp, :] = sigmoid(h2[sp] @ Wout + bout)
            int sp = tick - 3;
            if (sp >= 0 && sp < T_) {
                const ushort_t* A  = wsU + OFF_HBH + (4 + (sp & 1)) * 65536;
                const ushort_t* Bw = wsU + OFF_WOUT;
                frag_cd acc2[4] = {};
#pragma unroll 2
                for (int kb = 0; kb < 16; ++kb) {
                    frag_ab a = *(const frag_ab*)(A + (size_t)(r0o + m) * H_ + kb * 32 + koff);
#pragma unroll
                    for (int cf = 0; cf < 4; ++cf) {
                        frag_ab b = *(const frag_ab*)(Bw + ((size_t)(kb * 8 + och * 4 + cf) * 64 + lane) * 8);
                        acc2[cf] = __builtin_amdgcn_mfma_f32_16x16x32_bf16(a, b, acc2[cf], 0, 0, 0);
                    }
                }
#pragma unroll
                for (int cf = 0; cf < 4; ++cf)
#pragma unroll
                    for (int reg = 0; reg < 4; ++reg) {
                        int row = r0o + kq * 4 + reg;
                        int oc = och * 64 + cf * 16 + m;
                        out[((size_t)row * T_ + sp) * LD_ + oc] =
                            sig_(acc2[cf][reg] + bout[oc]);
                    }
            }
        }

        // ---- tick boundary: device-scope release + grid barrier ----
        __threadfence();
        grid.sync();
    }
}

extern "C" void kernel_launch(void* const* d_in, const int* in_sizes, int n_in,
                              void* d_out, int out_size, void* d_ws, size_t ws_size,
                              hipStream_t stream) {
    const float* noise = (const float*)d_in[0];
    const float* hcpl  = (const float*)d_in[1];
    const float* Wx0   = (const float*)d_in[2];
    const float* Wxr   = (const float*)d_in[3];
    const float* Wh    = (const float*)d_in[4];
    const float* Wc    = (const float*)d_in[5];
    const float* bias  = (const float*)d_in[6];
    const float* Wout  = (const float*)d_in[7];
    const float* bout  = (const float*)d_in[8];
    float* out = (float*)d_out;
    char* ws = (char*)d_ws;
    ushort_t* wsU = (ushort_t*)ws;

    auto launch_swz = [&](const float* src, unsigned ohi, unsigned olo, int K, int N) {
        int total = (K / 32) * (N / 16) * 64;
        swz_kernel<<<(total + 255) / 256, 256, 0, stream>>>(src, wsU + ohi, wsU + olo, K, N);
    };
    for (int l = 0; l < 3; ++l)
        launch_swz(Wh + (size_t)l * H_ * G_, OFF_WHH + l * 1048576u, OFF_WHL + l * 1048576u, H_, G_);
    launch_swz(Wx0, OFF_WXH, OFF_WXL, ND_, G_);
    for (int l = 0; l < 2; ++l)
        launch_swz(Wxr + (size_t)l * H_ * G_, OFF_WXH + 262144u + l * 1048576u,
                   OFF_WXL + 262144u + l * 1048576u, H_, G_);
    for (int l = 0; l < 3; ++l)
        launch_swz(Wc + (size_t)l * H_ * G_, OFF_WCH + l * 1048576u, OFF_WCL + l * 1048576u, H_, G_);
    launch_swz(Wout, OFF_WOUT, OFF_SCR, H_, LD_);
    cvt_kernel<<<(3 * B_ + 255) / 256 * H_ / H_ == 0 ? 1 : (3 * B_ * H_ + 255) / 256, 256, 0, stream>>>(
        hcpl, wsU + OFF_HCH, wsU + OFF_HCL, 3 * B_ * H_);
    cterm_kernel<<<192, 256, 0, stream>>>(ws, bias);

    // ONE persistent cooperative kernel replaces the 515 tick launches.
    void* args[] = {(void*)&noise, (void*)&ws, (void*)&out, (void*)&bout};
    hipLaunchCooperativeKernel((void*)tick_persist, dim3(194), dim3(512), args, 0, stream);
}

// Round 3
// 17451.874 us; speedup vs baseline: 2.3819x; 2.3819x over previous
//
#include <hip/hip_runtime.h>
#include <hip/hip_bf16.h>

// ============================================================================
// BilateralGenerator: 3-layer coupled LSTM, B=128 T=512 H=512 ND=128 LD=128.
//
// Round 9: r8 counters showed the persistent kernel's failure mode exactly:
// FETCH_SIZE 9.2GB/dispatch = 17.8MB/tick = the full weight set refetched
// every tick, because __threadfence()+grid.sync() (agent scope) invalidate
// the whole per-XCD L2 515 times. Fix = targeted coherence:
//  - h buffers (the ONLY cross-XCD data, 1.5MB/tick) move via sc0+sc1
//    flagged loads/stores (bypass non-coherent L2, coherent at fabric).
//    Depth-2 software pipeline on the sc1 A-loads (vmcnt(8)+sched_barrier).
//  - Custom relaxed grid barrier: monotonic counter, agent-scope RELAXED
//    atomics (no buffer_inv/wbl2), explicit vmcnt(0) drain before arrival.
//  - Weights/cterm/noise/c-state stay plain cached -> L2-resident across
//    all 515 ticks (c is block-private; cterm read-only after precompute).
// Math identical to r2..r7 (split-precision bf16 hi/lo GEMMs).
// ============================================================================

typedef unsigned short ushort_t;

using frag_ab = __attribute__((ext_vector_type(8))) short;  // 8 bf16
using frag_cd = __attribute__((ext_vector_type(4))) float;  // 4 fp32

#define B_   128
#define T_   512
#define ND_  128
#define H_   512
#define G_   2048   // 4*H
#define LD_  128

// ---- workspace layout (ushort element offsets into bf16 region) ----
#define OFF_WHH   0u          // Wh hi: 3 x 512*2048
#define OFF_WHL   3145728u    // Wh lo
#define OFF_WXH   6291456u    // Wx hi: Wx0 (128*2048) then Wxr[0], Wxr[1]
#define OFF_WXL   8650752u    // Wx lo
#define OFF_WCH   11010048u   // Wc hi: 3 x 512*2048
#define OFF_WCL   14155776u   // Wc lo
#define OFF_WOUT  17301504u   // Wout hi: 512*128
#define OFF_HCH   17367040u   // h_coupled hi: 3 x 128*512
#define OFF_HCL   17563648u   // h_coupled lo
#define OFF_HBH   17760256u   // h buf hi: 3 layers x 2 parity x 128*512
#define OFF_HBL   18153472u   // h buf lo
#define OFF_SCR   18546688u   // scratch (Wout lo, unused) + barrier counter
#define USH_BYTES 37224448u   // 18612224 ushorts * 2
#define BAR_BYTE  37093376u   // byte offset of barrier u32 (= OFF_SCR*2)
// ---- fp32 region (float element offsets from USH_BYTES) ----
#define FOFF_C     0u         // c state: 3 x 128*512
#define FOFF_CTERM 196608u    // Cterm: 3 x 128*2048

__device__ inline float sig_(float x)  { return 1.0f / (1.0f + __expf(-x)); }
__device__ inline float tanh_(float x) { return 2.0f / (1.0f + __expf(-2.0f * x)) - 1.0f; }

__device__ inline ushort_t f2b(float f) {
    __hip_bfloat16 h = __float2bfloat16(f);           // RNE
    return __builtin_bit_cast(unsigned short, h);
}
__device__ inline float b2f(ushort_t u) {
    unsigned int v = ((unsigned int)u) << 16;
    return __builtin_bit_cast(float, v);
}

// ---------------------------------------------------------------------------
// Weight swizzle + hi/lo split (round-2 verified).
// ---------------------------------------------------------------------------
__global__ void swz_kernel(const float* __restrict__ src,
                           ushort_t* __restrict__ dhi, ushort_t* __restrict__ dlo,
                           int K, int N) {
    int tid = blockIdx.x * 256 + threadIdx.x;
    int total = (K >> 5) * (N >> 4) * 64;
    if (tid >= total) return;
    int lane = tid & 63;
    int rest = tid >> 6;
    int NF = N >> 4;
    int nf = rest % NF;
    int kb = rest / NF;
    int kbase = kb * 32 + (lane >> 4) * 8;
    int n = nf * 16 + (lane & 15);
    union { ushort_t u[8]; uint4 v; } thi, tlo;
#pragma unroll
    for (int j = 0; j < 8; ++j) {
        float v = src[(size_t)(kbase + j) * N + n];
        ushort_t hi = f2b(v);
        thi.u[j] = hi;
        tlo.u[j] = f2b(v - b2f(hi));
    }
    *(uint4*)(dhi + (size_t)tid * 8) = thi.v;
    *(uint4*)(dlo + (size_t)tid * 8) = tlo.v;
}

__global__ void cvt_kernel(const float* __restrict__ src,
                           ushort_t* __restrict__ dhi, ushort_t* __restrict__ dlo, int n) {
    int i = blockIdx.x * 256 + threadIdx.x;
    if (i >= n) return;
    float v = src[i];
    ushort_t hi = f2b(v);
    dhi[i] = hi;
    dlo[i] = f2b(v - b2f(hi));
}

// ---------------------------------------------------------------------------
// Split-precision [16x64]-per-wave GEMM (round-2 verified) for cterm only.
// ---------------------------------------------------------------------------
__device__ inline void mfma_seg3(const ushort_t* __restrict__ Ah,
                                 const ushort_t* __restrict__ Al,
                                 const ushort_t* __restrict__ Bh,
                                 const ushort_t* __restrict__ Bl,
                                 int rowA, int cg, int nkb, frag_cd acc[4]) {
    int lane = threadIdx.x & 63;
    int koff = (lane >> 4) * 8;
#pragma unroll 2
    for (int kb = 0; kb < nkb; ++kb) {
        frag_ab ah = *(const frag_ab*)(Ah + (size_t)rowA * H_ + kb * 32 + koff);
        frag_ab al = *(const frag_ab*)(Al + (size_t)rowA * H_ + kb * 32 + koff);
#pragma unroll
        for (int q = 0; q < 4; ++q) {
            size_t bo = ((size_t)(kb * 128 + q * 32 + cg) * 64 + lane) * 8;
            frag_ab bh = *(const frag_ab*)(Bh + bo);
            frag_ab bl = *(const frag_ab*)(Bl + bo);
            acc[q] = __builtin_amdgcn_mfma_f32_16x16x32_bf16(ah, bh, acc[q], 0, 0, 0);
            acc[q] = __builtin_amdgcn_mfma_f32_16x16x32_bf16(ah, bl, acc[q], 0, 0, 0);
            acc[q] = __builtin_amdgcn_mfma_f32_16x16x32_bf16(al, bh, acc[q], 0, 0, 0);
        }
    }
}

__global__ __launch_bounds__(256) void cterm_kernel(char* __restrict__ ws,
                                                    const float* __restrict__ bias) {
    ushort_t* wsU = (ushort_t*)ws;
    float* wsF = (float*)(ws + USH_BYTES);
    int lane = threadIdx.x & 63, w = threadIdx.x >> 6;
    int bid = blockIdx.x;
    int layer = bid >> 6;
    int sub = bid & 63;
    int rg = sub >> 5, cg = sub & 31;
    int m = lane & 15, kq = lane >> 4;
    int r0 = rg * 64 + w * 16;
    int rowA = r0 + m;
    frag_cd acc[4] = {};
    mfma_seg3(wsU + OFF_HCH + layer * 65536, wsU + OFF_HCL + layer * 65536,
              wsU + OFF_WCH + (size_t)layer * 1048576, wsU + OFF_WCL + (size_t)layer * 1048576,
              rowA, cg, 16, acc);
    float* ct = wsF + FOFF_CTERM + (size_t)layer * 262144;
#pragma unroll
    for (int reg = 0; reg < 4; ++reg) {
        int row = r0 + kq * 4 + reg;
#pragma unroll
        for (int q = 0; q < 4; ++q) {
            int gcol = q * 512 + cg * 16 + m;
            ct[(size_t)row * G_ + gcol] = acc[q][reg] + bias[layer * G_ + gcol];
        }
    }
}

// ---------------------------------------------------------------------------
// sc0+sc1 coherent-load macros for cross-XCD h buffers. The pair-issue macro
// fills one kb-batch (4 rowtiles x hi/lo); vmcnt accounting: each batch = 8
// VMEM ops, and >=8 subsequent A-ops always follow a batch before its wait,
// so vmcnt(8) is safe regardless of compiler B-load interleave.
// ---------------------------------------------------------------------------
#define ISSUE_BATCH(SH, SL, KB)                                                 \
    {                                                                           \
        _Pragma("unroll")                                                       \
        for (int rt = 0; rt < 4; ++rt) {                                        \
            size_t ao = (size_t)(r0 + rt * 16 + m) * H_ + (size_t)(KB) * 32 + koff; \
            asm volatile("global_load_dwordx4 %0, %2, off sc0 sc1\n\t"          \
                         "global_load_dwordx4 %1, %3, off sc0 sc1"              \
                         : "=v"(SH[rt]), "=v"(SL[rt])                           \
                         : "v"(Ah + ao), "v"(Al + ao));                         \
        }                                                                       \
    }

#define MFMA_KB(SH, SL, KB)                                                     \
    {                                                                           \
        _Pragma("unroll")                                                       \
        for (int q = 0; q < 4; ++q) {                                           \
            size_t bo = ((size_t)((KB) * 128 + q * 32 + cg) * 64 + lane) * 8;   \
            frag_ab bh = *(const frag_ab*)(Bh + bo);                            \
            frag_ab bl = *(const frag_ab*)(Bl + bo);                            \
            _Pragma("unroll")                                                   \
            for (int rt = 0; rt < 4; ++rt) {                                    \
                acc[rt][q] = __builtin_amdgcn_mfma_f32_16x16x32_bf16(SH[rt], bh, acc[rt][q], 0, 0, 0); \
                acc[rt][q] = __builtin_amdgcn_mfma_f32_16x16x32_bf16(SH[rt], bl, acc[rt][q], 0, 0, 0); \
                acc[rt][q] = __builtin_amdgcn_mfma_f32_16x16x32_bf16(SL[rt], bh, acc[rt][q], 0, 0, 0); \
            }                                                                   \
        }                                                                       \
    }

#define WAIT_VM(N)                                              \
    asm volatile("s_waitcnt vmcnt(" #N ")" ::: "memory");       \
    __builtin_amdgcn_sched_barrier(0);

// Split-precision [64r x 64gc] K-quarter with sc1 A-loads, depth-2 pipeline.
__device__ inline void seg_sc(const ushort_t* __restrict__ Ah,
                              const ushort_t* __restrict__ Al,
                              const ushort_t* __restrict__ Bh,
                              const ushort_t* __restrict__ Bl,
                              int r0, int cg, int kb0, frag_cd acc[4][4]) {
    const int lane = threadIdx.x & 63;
    const int m = lane & 15;
    const int koff = (lane >> 4) * 8;
    frag_ab s0h[4], s0l[4], s1h[4], s1l[4];
    ISSUE_BATCH(s0h, s0l, kb0);
    ISSUE_BATCH(s1h, s1l, kb0 + 1);
    WAIT_VM(8);
    MFMA_KB(s0h, s0l, kb0);
    ISSUE_BATCH(s0h, s0l, kb0 + 2);
    WAIT_VM(8);
    MFMA_KB(s1h, s1l, kb0 + 1);
    ISSUE_BATCH(s1h, s1l, kb0 + 3);
    WAIT_VM(8);
    MFMA_KB(s0h, s0l, kb0 + 2);
    WAIT_VM(0);
    MFMA_KB(s1h, s1l, kb0 + 3);
}

// 2-byte coherent store (h hi/lo) — write-through past the non-coherent L2.
__device__ inline void stg_short_sc(ushort_t* p, ushort_t v) {
    asm volatile("global_store_short %0, %1, off sc0 sc1"
                 :: "v"(p), "v"((unsigned)v) : "memory");
}

// ---------------------------------------------------------------------------
// Relaxed grid barrier: monotonic counter, agent-scope relaxed atomics (no
// cache maintenance), explicit vmcnt(0) drains this thread's sc1 stores.
// ---------------------------------------------------------------------------
__device__ inline void gridbar(unsigned* bar, unsigned target) {
    asm volatile("s_waitcnt vmcnt(0)" ::: "memory");
    __syncthreads();
    if (threadIdx.x == 0) {
        __hip_atomic_fetch_add(bar, 1u, __ATOMIC_RELAXED, __HIP_MEMORY_SCOPE_AGENT);
        while (__hip_atomic_load(bar, __ATOMIC_RELAXED, __HIP_MEMORY_SCOPE_AGENT) < target)
            __builtin_amdgcn_s_sleep(1);
    }
    __syncthreads();
}

// ---------------------------------------------------------------------------
// Persistent pipeline: 194 blocks x 512 threads (8 waves), 515 internal ticks,
// relaxed grid barrier per tick. bid < 192: cell blocks, bid = rg64*96 +
// (layer*32+cg): [64r x 64gc] tile, waves 0-3 x-path K-quarters, 4-7 h-path;
// 8-way LDS partial exchange + fused epilogue. bid 192/193: out-proj.
// ---------------------------------------------------------------------------
__global__ __launch_bounds__(512, 2) void tick_persist(const float* __restrict__ noise,
                                                       char* __restrict__ ws,
                                                       float* __restrict__ out,
                                                       const float* __restrict__ bout) {
    __shared__ float ex[8][4096];   // 128 KB: per-wave [64r x 64gc] partials

    ushort_t* wsU = (ushort_t*)ws;
    float* wsF = (float*)(ws + USH_BYTES);
    unsigned* bar = (unsigned*)(ws + BAR_BYTE);
    const int lane = threadIdx.x & 63;
    const int w = threadIdx.x >> 6;       // wave id 0..7
    const int bid = blockIdx.x;
    const int m = lane & 15, kq = lane >> 4;
    const int koff = kq * 8;

    // ---- tick-invariant block identity ----
    const int rg64 = (bid < 192) ? (bid / 96) : 0;   // 0..1: 64-row group
    const int u    = (bid < 192) ? (bid % 96) : 0;   // XCD = u % 8
    const int layer = u >> 5;
    const int cg    = u & 31;
    const int r0    = rg64 * 64;
    const int owid = (bid - 192) * 8 + w;            // out-proj: 0..15
    const int org  = owid >> 1;                      // 8 rowgroups of 16
    const int och  = owid & 1;                       // 2 col halves of 64
    const int r0o  = org * 16;

    for (int tick = 0; tick < 515; ++tick) {
        if (bid < 192) {
            int s = tick - layer;
            if (s >= 0 && s < T_) {
                frag_cd acc[4][4] = {};

                if (w < 4) {
                    // ---- x-path K-quarter (layer0: noise K=128 -> kb = w)
                    if (layer == 0) {
                        const ushort_t* Bh = wsU + OFF_WXH;
                        const ushort_t* Bl = wsU + OFF_WXL;
                        int kb = w;
                        frag_ab ah[4], al[4];
#pragma unroll
                        for (int rt = 0; rt < 4; ++rt) {
                            const float* np = noise +
                                ((size_t)(r0 + rt * 16 + m) * T_ + s) * ND_ + kb * 32 + koff;
                            float4 f0 = *(const float4*)np;
                            float4 f1 = *(const float4*)(np + 4);
                            float xf[8] = {f0.x, f0.y, f0.z, f0.w, f1.x, f1.y, f1.z, f1.w};
#pragma unroll
                            for (int j = 0; j < 8; ++j) {
                                ushort_t hi = f2b(xf[j]);
                                ah[rt][j] = (short)hi;
                                al[rt][j] = (short)f2b(xf[j] - b2f(hi));
                            }
                        }
#pragma unroll
                        for (int q = 0; q < 4; ++q) {
                            size_t bo = ((size_t)(kb * 128 + q * 32 + cg) * 64 + lane) * 8;
                            frag_ab bh = *(const frag_ab*)(Bh + bo);
                            frag_ab bl = *(const frag_ab*)(Bl + bo);
#pragma unroll
                            for (int rt = 0; rt < 4; ++rt) {
                                acc[rt][q] = __builtin_amdgcn_mfma_f32_16x16x32_bf16(ah[rt], bh, acc[rt][q], 0, 0, 0);
                                acc[rt][q] = __builtin_amdgcn_mfma_f32_16x16x32_bf16(ah[rt], bl, acc[rt][q], 0, 0, 0);
                                acc[rt][q] = __builtin_amdgcn_mfma_f32_16x16x32_bf16(al[rt], bh, acc[rt][q], 0, 0, 0);
                            }
                        }
                    } else {
                        unsigned hb = (unsigned)((layer - 1) * 2 + (s & 1)) * 65536u;
                        seg_sc(wsU + OFF_HBH + hb, wsU + OFF_HBL + hb,
                               wsU + OFF_WXH + 262144u + (size_t)(layer - 1) * 1048576,
                               wsU + OFF_WXL + 262144u + (size_t)(layer - 1) * 1048576,
                               r0, cg, w * 4, acc);
                    }
                } else if (s > 0) {
                    // ---- h-path K-quarter (skip at s==0)
                    unsigned hb = (unsigned)(layer * 2 + ((s - 1) & 1)) * 65536u;
                    seg_sc(wsU + OFF_HBH + hb, wsU + OFF_HBL + hb,
                           wsU + OFF_WHH + (size_t)layer * 1048576,
                           wsU + OFF_WHL + (size_t)layer * 1048576,
                           r0, cg, (w - 4) * 4, acc);
                }

                // ---- write this wave's partial tile to LDS (static acc indices)
                {
                    float* eb = &ex[w][0];
#pragma unroll
                    for (int rt = 0; rt < 4; ++rt)
#pragma unroll
                        for (int q = 0; q < 4; ++q)
#pragma unroll
                            for (int reg = 0; reg < 4; ++reg)
                                eb[(rt * 16 + kq * 4 + reg) * 64 + q * 16 + m] = acc[rt][q][reg];
                }
                __syncthreads();

                // ---- combine 8 partials + activation epilogue: 2 elements/thread
                const float* ct = wsF + FOFF_CTERM + (size_t)layer * 262144;
                float* cst = wsF + FOFF_C + layer * 65536;
                ushort_t* hhi = wsU + OFF_HBH + (layer * 2 + (s & 1)) * 65536;
                ushort_t* hlo = wsU + OFF_HBL + (layer * 2 + (s & 1)) * 65536;
                int tid = threadIdx.x;
#pragma unroll
                for (int ee = 0; ee < 2; ++ee) {
                    int e = tid + ee * 512;     // 0..1023
                    int row = e >> 4;           // 0..63 within tile
                    int hcol = e & 15;
                    int grow = r0 + row;
                    int hc = cg * 16 + hcol;
                    int rb = row * 64 + hcol;
                    float gi = 0.0f, gf = 0.0f, gg = 0.0f, go = 0.0f;
#pragma unroll
                    for (int wv = 0; wv < 8; ++wv) {
                        gi += ex[wv][rb +  0];
                        gf += ex[wv][rb + 16];
                        gg += ex[wv][rb + 32];
                        go += ex[wv][rb + 48];
                    }
                    const float* cr = ct + (size_t)grow * G_ + hc;
                    gi += cr[0]; gf += cr[512]; gg += cr[1024]; go += cr[1536];
                    float cp = (s > 0) ? cst[grow * H_ + hc] : 0.0f;
                    float cn = sig_(gf) * cp + sig_(gi) * tanh_(gg);
                    float hn = sig_(go) * tanh_(cn);
                    cst[grow * H_ + hc] = cn;
                    ushort_t hi = f2b(hn);
                    stg_short_sc(hhi + grow * H_ + hc, hi);
                    stg_short_sc(hlo + grow * H_ + hc, f2b(hn - b2f(hi)));
                    if (s == T_ - 1)   // h_fin, fp32, no bf16 quantization
                        out[8388608u + (size_t)layer * 65536 + grow * H_ + hc] = hn;
                }
            }
        } else {
            // ---- output projection: out[:, sp, :] = sigmoid(h2[sp] @ Wout + bout)
            int sp = tick - 3;
            if (sp >= 0 && sp < T_) {
                const ushort_t* A  = wsU + OFF_HBH + (4 + (sp & 1)) * 65536;
                const ushort_t* Bw = wsU + OFF_WOUT;
                frag_ab af[16];
#pragma unroll
                for (int kb = 0; kb < 16; ++kb) {
                    const ushort_t* p = A + (size_t)(r0o + m) * H_ + kb * 32 + koff;
                    asm volatile("global_load_dwordx4 %0, %1, off sc0 sc1"
                                 : "=v"(af[kb]) : "v"(p));
                }
                asm volatile("s_waitcnt vmcnt(0)" ::: "memory");
                __builtin_amdgcn_sched_barrier(0);
                frag_cd acc2[4] = {};
#pragma unroll
                for (int kb = 0; kb < 16; ++kb) {
#pragma unroll
                    for (int cf = 0; cf < 4; ++cf) {
                        frag_ab b = *(const frag_ab*)(Bw + ((size_t)(kb * 8 + och * 4 + cf) * 64 + lane) * 8);
                        acc2[cf] = __builtin_amdgcn_mfma_f32_16x16x32_bf16(af[kb], b, acc2[cf], 0, 0, 0);
                    }
                }
#pragma unroll
                for (int cf = 0; cf < 4; ++cf)
#pragma unroll
                    for (int reg = 0; reg < 4; ++reg) {
                        int row = r0o + kq * 4 + reg;
                        int oc = och * 64 + cf * 16 + m;
                        out[((size_t)row * T_ + sp) * LD_ + oc] =
                            sig_(acc2[cf][reg] + bout[oc]);
                    }
            }
        }

        // ---- tick boundary: relaxed grid barrier (no cache maintenance) ----
        gridbar(bar, 194u * (unsigned)(tick + 1));
    }
}

extern "C" void kernel_launch(void* const* d_in, const int* in_sizes, int n_in,
                              void* d_out, int out_size, void* d_ws, size_t ws_size,
                              hipStream_t stream) {
    const float* noise = (const float*)d_in[0];
    const float* hcpl  = (const float*)d_in[1];
    const float* Wx0   = (const float*)d_in[2];
    const float* Wxr   = (const float*)d_in[3];
    const float* Wh    = (const float*)d_in[4];
    const float* Wc    = (const float*)d_in[5];
    const float* bias  = (const float*)d_in[6];
    const float* Wout  = (const float*)d_in[7];
    const float* bout  = (const float*)d_in[8];
    float* out = (float*)d_out;
    char* ws = (char*)d_ws;
    ushort_t* wsU = (ushort_t*)ws;

    auto launch_swz = [&](const float* src, unsigned ohi, unsigned olo, int K, int N) {
        int total = (K / 32) * (N / 16) * 64;
        swz_kernel<<<(total + 255) / 256, 256, 0, stream>>>(src, wsU + ohi, wsU + olo, K, N);
    };
    for (int l = 0; l < 3; ++l)
        launch_swz(Wh + (size_t)l * H_ * G_, OFF_WHH + l * 1048576u, OFF_WHL + l * 1048576u, H_, G_);
    launch_swz(Wx0, OFF_WXH, OFF_WXL, ND_, G_);
    for (int l = 0; l < 2; ++l)
        launch_swz(Wxr + (size_t)l * H_ * G_, OFF_WXH + 262144u + l * 1048576u,
                   OFF_WXL + 262144u + l * 1048576u, H_, G_);
    for (int l = 0; l < 3; ++l)
        launch_swz(Wc + (size_t)l * H_ * G_, OFF_WCH + l * 1048576u, OFF_WCL + l * 1048576u, H_, G_);
    launch_swz(Wout, OFF_WOUT, OFF_SCR, H_, LD_);
    cvt_kernel<<<(3 * B_ * H_ + 255) / 256, 256, 0, stream>>>(hcpl, wsU + OFF_HCH, wsU + OFF_HCL,
                                                              3 * B_ * H_);
    cterm_kernel<<<192, 256, 0, stream>>>(ws, bias);

    // zero the barrier counter (stream-ordered AFTER the Wout swz that writes
    // the scratch region it lives in; graph-capture-safe async memset)
    hipMemsetAsync(ws + BAR_BYTE, 0, 128, stream);

    // ONE persistent cooperative kernel replaces the 515 tick launches.
    void* args[] = {(void*)&noise, (void*)&ws, (void*)&out, (void*)&bout};
    hipLaunchCooperativeKernel((void*)tick_persist, dim3(194), dim3(512), args, 0, stream);
}

// Round 5
// 14564.644 us; speedup vs baseline: 2.8541x; 1.1982x over previous
//
#include <hip/hip_runtime.h>
#include <hip/hip_bf16.h>

// ============================================================================
// BilateralGenerator: 3-layer coupled LSTM, B=128 T=512 H=512 ND=128 LD=128.
//
// Round 11 = round 10 fixed:
//  - r10 crashed at launch: LDS 131080 B (ex[8][4096] + shmeta) vs the
//    131072 B that r8/r9 ran at. Fix: broadcast rank/nblk via ex[0], LDS
//    back to exactly 128 KB.
//  - r10's sc0-flagged staged loads were CU-scope (can hit stale L1). Fix:
//    plain cached loads (r7's proven seg_accum64k) + ONE `buffer_inv sc0`
//    (L1-only invalidate, L2 untouched) per tick after the staging barrier.
//  - Architecture unchanged: persistent kernel, 515 ticks, 2 relaxed grid
//    barriers/tick; per-XCD h staging (copy phase: 6 MB/tick system-scope
//    reads -> plain stores into own-L2 staging; 6.6x less fabric than r9);
//    weights plain-cached, L2-resident across all ticks.
// Math identical to r2..r9 (split-precision bf16 hi/lo GEMMs).
// ============================================================================

typedef unsigned short ushort_t;

using frag_ab = __attribute__((ext_vector_type(8))) short;  // 8 bf16
using frag_cd = __attribute__((ext_vector_type(4))) float;  // 4 fp32

#define B_   128
#define T_   512
#define ND_  128
#define H_   512
#define G_   2048   // 4*H
#define LD_  128

// ---- workspace layout (ushort element offsets into bf16 region) ----
#define OFF_WHH   0u          // Wh hi: 3 x 512*2048
#define OFF_WHL   3145728u    // Wh lo
#define OFF_WXH   6291456u    // Wx hi: Wx0 (128*2048) then Wxr[0], Wxr[1]
#define OFF_WXL   8650752u    // Wx lo
#define OFF_WCH   11010048u   // Wc hi: 3 x 512*2048 (DEAD after cterm -> staging)
#define OFF_WCL   14155776u   // Wc lo (dead after cterm)
#define OFF_WOUT  17301504u   // Wout hi: 512*128
#define OFF_HCH   17367040u   // h_coupled hi: 3 x 128*512
#define OFF_HCL   17563648u   // h_coupled lo
#define OFF_HBH   17760256u   // h buf hi: 3 layers x 2 parity x 128*512 (fabric)
#define OFF_HBL   18153472u   // h buf lo (fabric)
#define OFF_SCR   18546688u   // scratch (Wout lo dump) + barrier/ticket
#define USH_BYTES 37224448u   // 18612224 ushorts * 2
#define BAR_BYTE  37093376u   // byte offset of barrier u32 (= OFF_SCR*2)
// per-XCD staging: 8 x [3 layers x (hi|lo) x 128*512] in the dead Wc region
#define STAGE_BASE    OFF_WCH
#define STAGE_PER_XCD 393216u  // 3*2*65536 ushorts = 768 KB
// ---- fp32 region (float element offsets from USH_BYTES) ----
#define FOFF_C     0u         // c state: 3 x 128*512
#define FOFF_CTERM 196608u    // Cterm: 3 x 128*2048

__device__ inline float sig_(float x)  { return 1.0f / (1.0f + __expf(-x)); }
__device__ inline float tanh_(float x) { return 2.0f / (1.0f + __expf(-2.0f * x)) - 1.0f; }

__device__ inline ushort_t f2b(float f) {
    __hip_bfloat16 h = __float2bfloat16(f);           // RNE
    return __builtin_bit_cast(unsigned short, h);
}
__device__ inline float b2f(ushort_t u) {
    unsigned int v = ((unsigned int)u) << 16;
    return __builtin_bit_cast(float, v);
}

// ---------------------------------------------------------------------------
// Weight swizzle + hi/lo split (round-2 verified).
// ---------------------------------------------------------------------------
__global__ void swz_kernel(const float* __restrict__ src,
                           ushort_t* __restrict__ dhi, ushort_t* __restrict__ dlo,
                           int K, int N) {
    int tid = blockIdx.x * 256 + threadIdx.x;
    int total = (K >> 5) * (N >> 4) * 64;
    if (tid >= total) return;
    int lane = tid & 63;
    int rest = tid >> 6;
    int NF = N >> 4;
    int nf = rest % NF;
    int kb = rest / NF;
    int kbase = kb * 32 + (lane >> 4) * 8;
    int n = nf * 16 + (lane & 15);
    union { ushort_t u[8]; uint4 v; } thi, tlo;
#pragma unroll
    for (int j = 0; j < 8; ++j) {
        float v = src[(size_t)(kbase + j) * N + n];
        ushort_t hi = f2b(v);
        thi.u[j] = hi;
        tlo.u[j] = f2b(v - b2f(hi));
    }
    *(uint4*)(dhi + (size_t)tid * 8) = thi.v;
    *(uint4*)(dlo + (size_t)tid * 8) = tlo.v;
}

__global__ void cvt_kernel(const float* __restrict__ src,
                           ushort_t* __restrict__ dhi, ushort_t* __restrict__ dlo, int n) {
    int i = blockIdx.x * 256 + threadIdx.x;
    if (i >= n) return;
    float v = src[i];
    ushort_t hi = f2b(v);
    dhi[i] = hi;
    dlo[i] = f2b(v - b2f(hi));
}

// ---------------------------------------------------------------------------
// Split-precision [16x64]-per-wave GEMM (round-2 verified) for cterm only.
// ---------------------------------------------------------------------------
__device__ inline void mfma_seg3(const ushort_t* __restrict__ Ah,
                                 const ushort_t* __restrict__ Al,
                                 const ushort_t* __restrict__ Bh,
                                 const ushort_t* __restrict__ Bl,
                                 int rowA, int cg, int nkb, frag_cd acc[4]) {
    int lane = threadIdx.x & 63;
    int koff = (lane >> 4) * 8;
#pragma unroll 2
    for (int kb = 0; kb < nkb; ++kb) {
        frag_ab ah = *(const frag_ab*)(Ah + (size_t)rowA * H_ + kb * 32 + koff);
        frag_ab al = *(const frag_ab*)(Al + (size_t)rowA * H_ + kb * 32 + koff);
#pragma unroll
        for (int q = 0; q < 4; ++q) {
            size_t bo = ((size_t)(kb * 128 + q * 32 + cg) * 64 + lane) * 8;
            frag_ab bh = *(const frag_ab*)(Bh + bo);
            frag_ab bl = *(const frag_ab*)(Bl + bo);
            acc[q] = __builtin_amdgcn_mfma_f32_16x16x32_bf16(ah, bh, acc[q], 0, 0, 0);
            acc[q] = __builtin_amdgcn_mfma_f32_16x16x32_bf16(ah, bl, acc[q], 0, 0, 0);
            acc[q] = __builtin_amdgcn_mfma_f32_16x16x32_bf16(al, bh, acc[q], 0, 0, 0);
        }
    }
}

__global__ __launch_bounds__(256) void cterm_kernel(char* __restrict__ ws,
                                                    const float* __restrict__ bias) {
    ushort_t* wsU = (ushort_t*)ws;
    float* wsF = (float*)(ws + USH_BYTES);
    int lane = threadIdx.x & 63, w = threadIdx.x >> 6;
    int bid = blockIdx.x;
    int layer = bid >> 6;
    int sub = bid & 63;
    int rg = sub >> 5, cg = sub & 31;
    int m = lane & 15, kq = lane >> 4;
    int r0 = rg * 64 + w * 16;
    int rowA = r0 + m;
    frag_cd acc[4] = {};
    mfma_seg3(wsU + OFF_HCH + layer * 65536, wsU + OFF_HCL + layer * 65536,
              wsU + OFF_WCH + (size_t)layer * 1048576, wsU + OFF_WCL + (size_t)layer * 1048576,
              rowA, cg, 16, acc);
    float* ct = wsF + FOFF_CTERM + (size_t)layer * 262144;
#pragma unroll
    for (int reg = 0; reg < 4; ++reg) {
        int row = r0 + kq * 4 + reg;
#pragma unroll
        for (int q = 0; q < 4; ++q) {
            int gcol = q * 512 + cg * 16 + m;
            ct[(size_t)row * G_ + gcol] = acc[q][reg] + bias[layer * G_ + gcol];
        }
    }
}

// ---------------------------------------------------------------------------
// Split-precision [64 rows x 64 gcols]-per-wave K-chunk segment: 4 rowtiles,
// B frags reused 4x from registers (r7-proven, plain cached loads; A comes
// from XCD-local staging, fresh in L2 after per-tick buffer_inv sc0).
// ---------------------------------------------------------------------------
__device__ inline void seg_accum64k(const ushort_t* __restrict__ Ah,
                                    const ushort_t* __restrict__ Al,
                                    const ushort_t* __restrict__ Bh,
                                    const ushort_t* __restrict__ Bl,
                                    int r0, int cg, int kb0, int nkb, frag_cd acc[4][4]) {
    int lane = threadIdx.x & 63;
    int m = lane & 15;
    int koff = (lane >> 4) * 8;
#pragma unroll 2
    for (int kb = kb0; kb < kb0 + nkb; ++kb) {
        frag_ab ah[4], al[4];
#pragma unroll
        for (int rt = 0; rt < 4; ++rt) {
            size_t ao = (size_t)(r0 + rt * 16 + m) * H_ + kb * 32 + koff;
            ah[rt] = *(const frag_ab*)(Ah + ao);
            al[rt] = *(const frag_ab*)(Al + ao);
        }
#pragma unroll
        for (int q = 0; q < 4; ++q) {
            size_t bo = ((size_t)(kb * 128 + q * 32 + cg) * 64 + lane) * 8;
            frag_ab bh = *(const frag_ab*)(Bh + bo);
            frag_ab bl = *(const frag_ab*)(Bl + bo);
#pragma unroll
            for (int rt = 0; rt < 4; ++rt) {
                acc[rt][q] = __builtin_amdgcn_mfma_f32_16x16x32_bf16(ah[rt], bh, acc[rt][q], 0, 0, 0);
                acc[rt][q] = __builtin_amdgcn_mfma_f32_16x16x32_bf16(ah[rt], bl, acc[rt][q], 0, 0, 0);
                acc[rt][q] = __builtin_amdgcn_mfma_f32_16x16x32_bf16(al[rt], bh, acc[rt][q], 0, 0, 0);
            }
        }
    }
}

// 2-byte coherent store (h hi/lo) — write-through past the non-coherent L2.
__device__ inline void stg_short_sc(ushort_t* p, ushort_t v) {
    asm volatile("global_store_short %0, %1, off sc0 sc1"
                 :: "v"(p), "v"((unsigned)v) : "memory");
}

// ---------------------------------------------------------------------------
// Relaxed grid barrier: monotonic counter, agent-scope relaxed atomics (no
// cache maintenance), explicit vmcnt(0) drains this thread's pending stores.
// ---------------------------------------------------------------------------
__device__ inline void gridbar(unsigned* bar, unsigned target) {
    asm volatile("s_waitcnt vmcnt(0)" ::: "memory");
    __syncthreads();
    if (threadIdx.x == 0) {
        __hip_atomic_fetch_add(bar, 1u, __ATOMIC_RELAXED, __HIP_MEMORY_SCOPE_AGENT);
        while (__hip_atomic_load(bar, __ATOMIC_RELAXED, __HIP_MEMORY_SCOPE_AGENT) < target)
            __builtin_amdgcn_s_sleep(1);
    }
    __syncthreads();
}

// ---------------------------------------------------------------------------
// Persistent pipeline: 194 blocks x 512 threads, 515 ticks, 2 barriers/tick.
// Tick = [copy: fabric h -> XCD-local staging] bar [buffer_inv sc0; compute].
// Cell blocks bid<192: bid = rg64*96 + (layer*32+cg), [64r x 64gc] tile,
// waves 0-3 x-path K-quarters, 4-7 h-path; 8-way LDS partial exchange +
// fused epilogue (h -> fabric via sc1). bid 192/193: out-proj from staging.
// ---------------------------------------------------------------------------
__global__ __launch_bounds__(512, 2) void tick_persist(const float* __restrict__ noise,
                                                       char* __restrict__ ws,
                                                       float* __restrict__ out,
                                                       const float* __restrict__ bout) {
    __shared__ float ex[8][4096];   // 128 KB exactly (r8/r9-proven size)

    ushort_t* wsU = (ushort_t*)ws;
    float* wsF = (float*)(ws + USH_BYTES);
    unsigned* bar = (unsigned*)(ws + BAR_BYTE);
    unsigned* ticket = (unsigned*)(ws + BAR_BYTE + 64);
    const int lane = threadIdx.x & 63;
    const int w = threadIdx.x >> 6;       // wave id 0..7
    const int bid = blockIdx.x;
    const int m = lane & 15, kq = lane >> 4;
    const int koff = kq * 8;

    // ---- XCD self-identification + per-XCD rank election (broadcast via ex)
    unsigned xcc_s;
    asm volatile("s_getreg_b32 %0, hwreg(HW_REG_XCC_ID)" : "=s"(xcc_s));
    const unsigned xcc = xcc_s & 7u;
    volatile unsigned* exu = (volatile unsigned*)&ex[0][0];
    if (threadIdx.x == 0)
        exu[0] = __hip_atomic_fetch_add(&ticket[xcc], 1u, __ATOMIC_RELAXED,
                                        __HIP_MEMORY_SCOPE_AGENT);
    __syncthreads();
    const unsigned rank = exu[0];
    unsigned barphase = 0;
    gridbar(bar, 194u * ++barphase);
    if (threadIdx.x == 0)
        exu[0] = __hip_atomic_load(&ticket[xcc], __ATOMIC_RELAXED,
                                   __HIP_MEMORY_SCOPE_AGENT);
    __syncthreads();
    const unsigned nblk = exu[0];
    const unsigned stbase = STAGE_BASE + xcc * STAGE_PER_XCD;

    // ---- tick-invariant block identity ----
    const int rg64 = (bid < 192) ? (bid / 96) : 0;   // 0..1: 64-row group
    const int u    = (bid < 192) ? (bid % 96) : 0;
    const int layer = u >> 5;
    const int cg    = u & 31;
    const int r0    = rg64 * 64;
    const int owid = (bid - 192) * 8 + w;            // out-proj: 0..15
    const int org  = owid >> 1;                      // 8 rowgroups of 16
    const int och  = owid & 1;                       // 2 col halves of 64
    const int r0o  = org * 16;

    for (int tick = 0; tick < 515; ++tick) {
        // ================= copy phase: fabric h -> XCD-local staging =======
        if (tick > 0) {
            const int sw0 = tick - 1, sw1 = tick - 2, sw2 = tick - 3;
            const bool e0 = (sw0 >= 0 && sw0 < T_);
            const bool e1 = (sw1 >= 0 && sw1 < T_);
            const bool e2 = (sw2 >= 0 && sw2 < T_);
            const unsigned p0 = (unsigned)sw0 & 1u;
            const unsigned p1 = (unsigned)sw1 & 1u;
            const unsigned p2 = (unsigned)sw2 & 1u;
            for (unsigned sl = rank * 512u + threadIdx.x; sl < 8192u; sl += nblk * 512u) {
                const unsigned off = sl * 8u;
                uint4 v0h, v0l, v1h, v1l, v2h, v2l;
                if (e0) {
                    const ushort_t* sh = wsU + OFF_HBH + (0u * 2u + p0) * 65536u + off;
                    const ushort_t* slo = wsU + OFF_HBL + (0u * 2u + p0) * 65536u + off;
                    asm volatile("global_load_dwordx4 %0, %2, off sc0 sc1\n\t"
                                 "global_load_dwordx4 %1, %3, off sc0 sc1"
                                 : "=v"(v0h), "=v"(v0l) : "v"(sh), "v"(slo));
                }
                if (e1) {
                    const ushort_t* sh = wsU + OFF_HBH + (1u * 2u + p1) * 65536u + off;
                    const ushort_t* slo = wsU + OFF_HBL + (1u * 2u + p1) * 65536u + off;
                    asm volatile("global_load_dwordx4 %0, %2, off sc0 sc1\n\t"
                                 "global_load_dwordx4 %1, %3, off sc0 sc1"
                                 : "=v"(v1h), "=v"(v1l) : "v"(sh), "v"(slo));
                }
                if (e2) {
                    const ushort_t* sh = wsU + OFF_HBH + (2u * 2u + p2) * 65536u + off;
                    const ushort_t* slo = wsU + OFF_HBL + (2u * 2u + p2) * 65536u + off;
                    asm volatile("global_load_dwordx4 %0, %2, off sc0 sc1\n\t"
                                 "global_load_dwordx4 %1, %3, off sc0 sc1"
                                 : "=v"(v2h), "=v"(v2l) : "v"(sh), "v"(slo));
                }
                asm volatile("s_waitcnt vmcnt(0)" ::: "memory");
                if (e0) {
                    *(uint4*)(wsU + stbase + 0u * 131072u + off) = v0h;
                    *(uint4*)(wsU + stbase + 0u * 131072u + 65536u + off) = v0l;
                }
                if (e1) {
                    *(uint4*)(wsU + stbase + 1u * 131072u + off) = v1h;
                    *(uint4*)(wsU + stbase + 1u * 131072u + 65536u + off) = v1l;
                }
                if (e2) {
                    *(uint4*)(wsU + stbase + 2u * 131072u + off) = v2h;
                    *(uint4*)(wsU + stbase + 2u * 131072u + 65536u + off) = v2l;
                }
            }
        }
        gridbar(bar, 194u * ++barphase);   // staging in own L2 (vmcnt(0) inside)

        // L1-only invalidate: staged lines may be stale in this CU's L1 from
        // last tick; L2 (weights + fresh staging) untouched.
        asm volatile("buffer_inv sc0" ::: "memory");

        // ================= compute phase ===================================
        if (bid < 192) {
            int s = tick - layer;
            if (s >= 0 && s < T_) {
                frag_cd acc[4][4] = {};

                if (w < 4) {
                    // ---- x-path K-quarter (layer0: noise K=128 -> kb = w)
                    if (layer == 0) {
                        const ushort_t* Bh = wsU + OFF_WXH;
                        const ushort_t* Bl = wsU + OFF_WXL;
                        int kb = w;
                        frag_ab ah[4], al[4];
#pragma unroll
                        for (int rt = 0; rt < 4; ++rt) {
                            const float* np = noise +
                                ((size_t)(r0 + rt * 16 + m) * T_ + s) * ND_ + kb * 32 + koff;
                            float4 f0 = *(const float4*)np;
                            float4 f1 = *(const float4*)(np + 4);
                            float xf[8] = {f0.x, f0.y, f0.z, f0.w, f1.x, f1.y, f1.z, f1.w};
#pragma unroll
                            for (int j = 0; j < 8; ++j) {
                                ushort_t hi = f2b(xf[j]);
                                ah[rt][j] = (short)hi;
                                al[rt][j] = (short)f2b(xf[j] - b2f(hi));
                            }
                        }
#pragma unroll
                        for (int q = 0; q < 4; ++q) {
                            size_t bo = ((size_t)(kb * 128 + q * 32 + cg) * 64 + lane) * 8;
                            frag_ab bh = *(const frag_ab*)(Bh + bo);
                            frag_ab bl = *(const frag_ab*)(Bl + bo);
#pragma unroll
                            for (int rt = 0; rt < 4; ++rt) {
                                acc[rt][q] = __builtin_amdgcn_mfma_f32_16x16x32_bf16(ah[rt], bh, acc[rt][q], 0, 0, 0);
                                acc[rt][q] = __builtin_amdgcn_mfma_f32_16x16x32_bf16(ah[rt], bl, acc[rt][q], 0, 0, 0);
                                acc[rt][q] = __builtin_amdgcn_mfma_f32_16x16x32_bf16(al[rt], bh, acc[rt][q], 0, 0, 0);
                            }
                        }
                    } else {
                        // A = staged h[layer-1] (fresh in own L2)
                        seg_accum64k(wsU + stbase + (unsigned)(layer - 1) * 131072u,
                                     wsU + stbase + (unsigned)(layer - 1) * 131072u + 65536u,
                                     wsU + OFF_WXH + 262144u + (size_t)(layer - 1) * 1048576,
                                     wsU + OFF_WXL + 262144u + (size_t)(layer - 1) * 1048576,
                                     r0, cg, w * 4, 4, acc);
                    }
                } else if (s > 0) {
                    // A = staged h[layer] (fresh in own L2)
                    seg_accum64k(wsU + stbase + (unsigned)layer * 131072u,
                                 wsU + stbase + (unsigned)layer * 131072u + 65536u,
                                 wsU + OFF_WHH + (size_t)layer * 1048576,
                                 wsU + OFF_WHL + (size_t)layer * 1048576,
                                 r0, cg, (w - 4) * 4, 4, acc);
                }

                // ---- write this wave's partial tile to LDS (static acc indices)
                {
                    float* eb = &ex[w][0];
#pragma unroll
                    for (int rt = 0; rt < 4; ++rt)
#pragma unroll
                        for (int q = 0; q < 4; ++q)
#pragma unroll
                            for (int reg = 0; reg < 4; ++reg)
                                eb[(rt * 16 + kq * 4 + reg) * 64 + q * 16 + m] = acc[rt][q][reg];
                }
                __syncthreads();

                // ---- combine 8 partials + activation epilogue: 2 elements/thread
                const float* ct = wsF + FOFF_CTERM + (size_t)layer * 262144;
                float* cst = wsF + FOFF_C + layer * 65536;
                ushort_t* hhi = wsU + OFF_HBH + (layer * 2 + (s & 1)) * 65536;
                ushort_t* hlo = wsU + OFF_HBL + (layer * 2 + (s & 1)) * 65536;
                int tid = threadIdx.x;
#pragma unroll
                for (int ee = 0; ee < 2; ++ee) {
                    int e = tid + ee * 512;     // 0..1023
                    int row = e >> 4;           // 0..63 within tile
                    int hcol = e & 15;
                    int grow = r0 + row;
                    int hc = cg * 16 + hcol;
                    int rb = row * 64 + hcol;
                    float gi = 0.0f, gf = 0.0f, gg = 0.0f, go = 0.0f;
#pragma unroll
                    for (int wv = 0; wv < 8; ++wv) {
                        gi += ex[wv][rb +  0];
                        gf += ex[wv][rb + 16];
                        gg += ex[wv][rb + 32];
                        go += ex[wv][rb + 48];
                    }
                    const float* cr = ct + (size_t)grow * G_ + hc;
                    gi += cr[0]; gf += cr[512]; gg += cr[1024]; go += cr[1536];
                    float cp = (s > 0) ? cst[grow * H_ + hc] : 0.0f;
                    float cn = sig_(gf) * cp + sig_(gi) * tanh_(gg);
                    float hn = sig_(go) * tanh_(cn);
                    cst[grow * H_ + hc] = cn;
                    ushort_t hi = f2b(hn);
                    stg_short_sc(hhi + grow * H_ + hc, hi);
                    stg_short_sc(hlo + grow * H_ + hc, f2b(hn - b2f(hi)));
                    if (s == T_ - 1)   // h_fin, fp32, no bf16 quantization
                        out[8388608u + (size_t)layer * 65536 + grow * H_ + hc] = hn;
                }
            }
        } else {
            // ---- output projection: out[:, sp, :] = sigmoid(h2[sp] @ Wout + bout)
            int sp = tick - 3;
            if (sp >= 0 && sp < T_) {
                const ushort_t* A  = wsU + stbase + 2u * 131072u;   // staged h2 hi
                const ushort_t* Bw = wsU + OFF_WOUT;
                frag_cd acc2[4] = {};
#pragma unroll 2
                for (int kb = 0; kb < 16; ++kb) {
                    frag_ab a = *(const frag_ab*)(A + (size_t)(r0o + m) * H_ + kb * 32 + koff);
#pragma unroll
                    for (int cf = 0; cf < 4; ++cf) {
                        frag_ab b = *(const frag_ab*)(Bw + ((size_t)(kb * 8 + och * 4 + cf) * 64 + lane) * 8);
                        acc2[cf] = __builtin_amdgcn_mfma_f32_16x16x32_bf16(a, b, acc2[cf], 0, 0, 0);
                    }
                }
#pragma unroll
                for (int cf = 0; cf < 4; ++cf)
#pragma unroll
                    for (int reg = 0; reg < 4; ++reg) {
                        int row = r0o + kq * 4 + reg;
                        int oc = och * 64 + cf * 16 + m;
                        out[((size_t)row * T_ + sp) * LD_ + oc] =
                            sig_(acc2[cf][reg] + bout[oc]);
                    }
            }
        }

        gridbar(bar, 194u * ++barphase);   // tick boundary (vmcnt(0) inside)
    }
}

extern "C" void kernel_launch(void* const* d_in, const int* in_sizes, int n_in,
                              void* d_out, int out_size, void* d_ws, size_t ws_size,
                              hipStream_t stream) {
    const float* noise = (const float*)d_in[0];
    const float* hcpl  = (const float*)d_in[1];
    const float* Wx0   = (const float*)d_in[2];
    const float* Wxr   = (const float*)d_in[3];
    const float* Wh    = (const float*)d_in[4];
    const float* Wc    = (const float*)d_in[5];
    const float* bias  = (const float*)d_in[6];
    const float* Wout  = (const float*)d_in[7];
    const float* bout  = (const float*)d_in[8];
    float* out = (float*)d_out;
    char* ws = (char*)d_ws;
    ushort_t* wsU = (ushort_t*)ws;

    auto launch_swz = [&](const float* src, unsigned ohi, unsigned olo, int K, int N) {
        int total = (K / 32) * (N / 16) * 64;
        swz_kernel<<<(total + 255) / 256, 256, 0, stream>>>(src, wsU + ohi, wsU + olo, K, N);
    };
    for (int l = 0; l < 3; ++l)
        launch_swz(Wh + (size_t)l * H_ * G_, OFF_WHH + l * 1048576u, OFF_WHL + l * 1048576u, H_, G_);
    launch_swz(Wx0, OFF_WXH, OFF_WXL, ND_, G_);
    for (int l = 0; l < 2; ++l)
        launch_swz(Wxr + (size_t)l * H_ * G_, OFF_WXH + 262144u + l * 1048576u,
                   OFF_WXL + 262144u + l * 1048576u, H_, G_);
    for (int l = 0; l < 3; ++l)
        launch_swz(Wc + (size_t)l * H_ * G_, OFF_WCH + l * 1048576u, OFF_WCL + l * 1048576u, H_, G_);
    launch_swz(Wout, OFF_WOUT, OFF_SCR, H_, LD_);
    cvt_kernel<<<(3 * B_ * H_ + 255) / 256, 256, 0, stream>>>(hcpl, wsU + OFF_HCH, wsU + OFF_HCL,
                                                              3 * B_ * H_);
    cterm_kernel<<<192, 256, 0, stream>>>(ws, bias);

    // zero barrier counter + per-XCD tickets (stream-ordered after the Wout
    // swz that writes the scratch region; graph-capture-safe async memset)
    hipMemsetAsync(ws + BAR_BYTE, 0, 128, stream);

    // ONE persistent cooperative kernel replaces the 515 tick launches.
    void* args[] = {(void*)&noise, (void*)&ws, (void*)&out, (void*)&bout};
    hipLaunchCooperativeKernel((void*)tick_persist, dim3(194), dim3(512), args, 0, stream);
}

// Round 6
// 12813.370 us; speedup vs baseline: 3.2441x; 1.1367x over previous
//
#include <hip/hip_runtime.h>
#include <hip/hip_bf16.h>

// ============================================================================
// BilateralGenerator: 3-layer coupled LSTM, B=128 T=512 H=512 ND=128 LD=128.
//
// Round 12: r11 counters: FETCH 20MB/tick, WRITE 7.6MB/tick -> L2 thrash
// (per-XCD footprint 4.2MB > 4MB L2; staging+weights cycle through L3).
// Invariant across r7/r9/r11: L2-miss traffic served at ~1.2 TB/s -> the
// objective is MINIMIZE L2-MISS BYTES/TICK. This round:
//  - Layer-clustered tile map: bid -> (x8=bid&7, p=x8*12+(j>>1), rg=j&1).
//    Both rowgroups of a tile stay on one XCD (weight dedup kept); each
//    XCD's tiles span 1-2 layers.
//  - Dynamic per-XCD need-mask (agent atomics OR by actual co-resident
//    blocks): copy phase stages only needed h layers -> ~4.25MB/tick fabric
//    (was 6), staging 256-512KB/XCD (was 768).
//  - cterm: tiled per-(layer,cg) layout (full 128B-line use, was 2x
//    overfetch) + `nt` reads (no L2 allocate -> weights not evicted).
//  - Unchanged r11-proven parts: XCC_ID election, sc1 copy loads, plain
//    staged GEMM loads + per-tick buffer_inv sc0, relaxed grid barriers.
// Math identical to r2..r11 (split-precision bf16 hi/lo GEMMs).
// ============================================================================

typedef unsigned short ushort_t;

using frag_ab = __attribute__((ext_vector_type(8))) short;  // 8 bf16
using frag_cd = __attribute__((ext_vector_type(4))) float;  // 4 fp32

#define B_   128
#define T_   512
#define ND_  128
#define H_   512
#define G_   2048   // 4*H
#define LD_  128

// ---- workspace layout (ushort element offsets into bf16 region) ----
#define OFF_WHH   0u          // Wh hi: 3 x 512*2048
#define OFF_WHL   3145728u    // Wh lo
#define OFF_WXH   6291456u    // Wx hi: Wx0 (128*2048) then Wxr[0], Wxr[1]
#define OFF_WXL   8650752u    // Wx lo
#define OFF_WCH   11010048u   // Wc hi: 3 x 512*2048 (DEAD after cterm -> staging)
#define OFF_WCL   14155776u   // Wc lo (dead after cterm)
#define OFF_WOUT  17301504u   // Wout hi: 512*128
#define OFF_HCH   17367040u   // h_coupled hi: 3 x 128*512
#define OFF_HCL   17563648u   // h_coupled lo
#define OFF_HBH   17760256u   // h buf hi: 3 layers x 2 parity x 128*512 (fabric)
#define OFF_HBL   18153472u   // h buf lo (fabric)
#define OFF_SCR   18546688u   // scratch (Wout lo dump) + barrier/ticket/mask
#define USH_BYTES 37224448u   // 18612224 ushorts * 2
#define BAR_BYTE  37093376u   // byte offset of barrier u32 (= OFF_SCR*2)
// per-XCD staging: 8 x [3 layers x (hi|lo) x 128*512] in the dead Wc region
#define STAGE_BASE    OFF_WCH
#define STAGE_PER_XCD 393216u  // 3*2*65536 ushorts = 768 KB
// ---- fp32 region (float element offsets from USH_BYTES) ----
#define FOFF_C     0u         // c state: 3 x 128*512
#define FOFF_CTERM 196608u    // Cterm TILED: [layer*32+cg][128 rows][64]

__device__ inline float sig_(float x)  { return 1.0f / (1.0f + __expf(-x)); }
__device__ inline float tanh_(float x) { return 2.0f / (1.0f + __expf(-2.0f * x)) - 1.0f; }

__device__ inline ushort_t f2b(float f) {
    __hip_bfloat16 h = __float2bfloat16(f);           // RNE
    return __builtin_bit_cast(unsigned short, h);
}
__device__ inline float b2f(ushort_t u) {
    unsigned int v = ((unsigned int)u) << 16;
    return __builtin_bit_cast(float, v);
}

// ---------------------------------------------------------------------------
// Weight swizzle + hi/lo split (round-2 verified).
// ---------------------------------------------------------------------------
__global__ void swz_kernel(const float* __restrict__ src,
                           ushort_t* __restrict__ dhi, ushort_t* __restrict__ dlo,
                           int K, int N) {
    int tid = blockIdx.x * 256 + threadIdx.x;
    int total = (K >> 5) * (N >> 4) * 64;
    if (tid >= total) return;
    int lane = tid & 63;
    int rest = tid >> 6;
    int NF = N >> 4;
    int nf = rest % NF;
    int kb = rest / NF;
    int kbase = kb * 32 + (lane >> 4) * 8;
    int n = nf * 16 + (lane & 15);
    union { ushort_t u[8]; uint4 v; } thi, tlo;
#pragma unroll
    for (int j = 0; j < 8; ++j) {
        float v = src[(size_t)(kbase + j) * N + n];
        ushort_t hi = f2b(v);
        thi.u[j] = hi;
        tlo.u[j] = f2b(v - b2f(hi));
    }
    *(uint4*)(dhi + (size_t)tid * 8) = thi.v;
    *(uint4*)(dlo + (size_t)tid * 8) = tlo.v;
}

__global__ void cvt_kernel(const float* __restrict__ src,
                           ushort_t* __restrict__ dhi, ushort_t* __restrict__ dlo, int n) {
    int i = blockIdx.x * 256 + threadIdx.x;
    if (i >= n) return;
    float v = src[i];
    ushort_t hi = f2b(v);
    dhi[i] = hi;
    dlo[i] = f2b(v - b2f(hi));
}

// ---------------------------------------------------------------------------
// Split-precision [16x64]-per-wave GEMM (round-2 verified) for cterm only.
// ---------------------------------------------------------------------------
__device__ inline void mfma_seg3(const ushort_t* __restrict__ Ah,
                                 const ushort_t* __restrict__ Al,
                                 const ushort_t* __restrict__ Bh,
                                 const ushort_t* __restrict__ Bl,
                                 int rowA, int cg, int nkb, frag_cd acc[4]) {
    int lane = threadIdx.x & 63;
    int koff = (lane >> 4) * 8;
#pragma unroll 2
    for (int kb = 0; kb < nkb; ++kb) {
        frag_ab ah = *(const frag_ab*)(Ah + (size_t)rowA * H_ + kb * 32 + koff);
        frag_ab al = *(const frag_ab*)(Al + (size_t)rowA * H_ + kb * 32 + koff);
#pragma unroll
        for (int q = 0; q < 4; ++q) {
            size_t bo = ((size_t)(kb * 128 + q * 32 + cg) * 64 + lane) * 8;
            frag_ab bh = *(const frag_ab*)(Bh + bo);
            frag_ab bl = *(const frag_ab*)(Bl + bo);
            acc[q] = __builtin_amdgcn_mfma_f32_16x16x32_bf16(ah, bh, acc[q], 0, 0, 0);
            acc[q] = __builtin_amdgcn_mfma_f32_16x16x32_bf16(ah, bl, acc[q], 0, 0, 0);
            acc[q] = __builtin_amdgcn_mfma_f32_16x16x32_bf16(al, bh, acc[q], 0, 0, 0);
        }
    }
}

// cterm written TILED: ct[(layer*32+cg)*128 + row][64] with 64 = q*16+m.
__global__ __launch_bounds__(256) void cterm_kernel(char* __restrict__ ws,
                                                    const float* __restrict__ bias) {
    ushort_t* wsU = (ushort_t*)ws;
    float* wsF = (float*)(ws + USH_BYTES);
    int lane = threadIdx.x & 63, w = threadIdx.x >> 6;
    int bid = blockIdx.x;
    int layer = bid >> 6;
    int sub = bid & 63;
    int rg = sub >> 5, cg = sub & 31;
    int m = lane & 15, kq = lane >> 4;
    int r0 = rg * 64 + w * 16;
    int rowA = r0 + m;
    frag_cd acc[4] = {};
    mfma_seg3(wsU + OFF_HCH + layer * 65536, wsU + OFF_HCL + layer * 65536,
              wsU + OFF_WCH + (size_t)layer * 1048576, wsU + OFF_WCL + (size_t)layer * 1048576,
              rowA, cg, 16, acc);
    float* ct = wsF + FOFF_CTERM + ((size_t)(layer * 32 + cg) * 128) * 64;
#pragma unroll
    for (int reg = 0; reg < 4; ++reg) {
        int row = r0 + kq * 4 + reg;
#pragma unroll
        for (int q = 0; q < 4; ++q) {
            int gcol = q * 512 + cg * 16 + m;
            ct[(size_t)row * 64 + q * 16 + m] = acc[q][reg] + bias[layer * G_ + gcol];
        }
    }
}

// ---------------------------------------------------------------------------
// Split-precision [64 rows x 64 gcols]-per-wave K-chunk segment: 4 rowtiles,
// B frags reused 4x from registers (r7-proven, plain cached loads; A comes
// from XCD-local staging, fresh in L2 after per-tick buffer_inv sc0).
// ---------------------------------------------------------------------------
__device__ inline void seg_accum64k(const ushort_t* __restrict__ Ah,
                                    const ushort_t* __restrict__ Al,
                                    const ushort_t* __restrict__ Bh,
                                    const ushort_t* __restrict__ Bl,
                                    int r0, int cg, int kb0, int nkb, frag_cd acc[4][4]) {
    int lane = threadIdx.x & 63;
    int m = lane & 15;
    int koff = (lane >> 4) * 8;
#pragma unroll 2
    for (int kb = kb0; kb < kb0 + nkb; ++kb) {
        frag_ab ah[4], al[4];
#pragma unroll
        for (int rt = 0; rt < 4; ++rt) {
            size_t ao = (size_t)(r0 + rt * 16 + m) * H_ + kb * 32 + koff;
            ah[rt] = *(const frag_ab*)(Ah + ao);
            al[rt] = *(const frag_ab*)(Al + ao);
        }
#pragma unroll
        for (int q = 0; q < 4; ++q) {
            size_t bo = ((size_t)(kb * 128 + q * 32 + cg) * 64 + lane) * 8;
            frag_ab bh = *(const frag_ab*)(Bh + bo);
            frag_ab bl = *(const frag_ab*)(Bl + bo);
#pragma unroll
            for (int rt = 0; rt < 4; ++rt) {
                acc[rt][q] = __builtin_amdgcn_mfma_f32_16x16x32_bf16(ah[rt], bh, acc[rt][q], 0, 0, 0);
                acc[rt][q] = __builtin_amdgcn_mfma_f32_16x16x32_bf16(ah[rt], bl, acc[rt][q], 0, 0, 0);
                acc[rt][q] = __builtin_amdgcn_mfma_f32_16x16x32_bf16(al[rt], bh, acc[rt][q], 0, 0, 0);
            }
        }
    }
}

// 2-byte coherent store (h hi/lo) — write-through past the non-coherent L2.
__device__ inline void stg_short_sc(ushort_t* p, ushort_t v) {
    asm volatile("global_store_short %0, %1, off sc0 sc1"
                 :: "v"(p), "v"((unsigned)v) : "memory");
}

// ---------------------------------------------------------------------------
// Relaxed grid barrier: monotonic counter, agent-scope relaxed atomics (no
// cache maintenance), explicit vmcnt(0) drains this thread's pending stores.
// ---------------------------------------------------------------------------
__device__ inline void gridbar(unsigned* bar, unsigned target) {
    asm volatile("s_waitcnt vmcnt(0)" ::: "memory");
    __syncthreads();
    if (threadIdx.x == 0) {
        __hip_atomic_fetch_add(bar, 1u, __ATOMIC_RELAXED, __HIP_MEMORY_SCOPE_AGENT);
        while (__hip_atomic_load(bar, __ATOMIC_RELAXED, __HIP_MEMORY_SCOPE_AGENT) < target)
            __builtin_amdgcn_s_sleep(1);
    }
    __syncthreads();
}

// ---------------------------------------------------------------------------
// Persistent pipeline: 194 blocks x 512 threads, 515 ticks, 2 barriers/tick.
// Tile map (layer-clustered): cb=bid<192: x8=cb&7, j=cb>>3, p=x8*12+(j>>1),
// layer=p>>5, cg=p&31, rg64=j&1. Copy phase stages only layers in the
// per-XCD need-mask. bid 192/193: out-proj from staged h2.
// ---------------------------------------------------------------------------
__global__ __launch_bounds__(512, 2) void tick_persist(const float* __restrict__ noise,
                                                       char* __restrict__ ws,
                                                       float* __restrict__ out,
                                                       const float* __restrict__ bout) {
    __shared__ float ex[8][4096];   // 128 KB exactly (r8/r9-proven size)

    ushort_t* wsU = (ushort_t*)ws;
    float* wsF = (float*)(ws + USH_BYTES);
    unsigned* bar = (unsigned*)(ws + BAR_BYTE);
    unsigned* ticket = (unsigned*)(ws + BAR_BYTE + 64);       // 8 x u32
    unsigned* needmask = (unsigned*)(ws + BAR_BYTE + 96);     // 8 x u32
    const int lane = threadIdx.x & 63;
    const int w = threadIdx.x >> 6;       // wave id 0..7
    const int bid = blockIdx.x;
    const int m = lane & 15, kq = lane >> 4;
    const int koff = kq * 8;

    // ---- tick-invariant block identity (layer-clustered map) ----
    const int cb   = (bid < 192) ? bid : 0;
    const int x8   = cb & 7, jj = cb >> 3;
    const int pp   = x8 * 12 + (jj >> 1);
    const int layer = pp >> 5;
    const int cg    = pp & 31;
    const int rg64  = jj & 1;
    const int r0    = rg64 * 64;
    const int owid = (bid - 192) * 8 + w;            // out-proj: 0..15
    const int org  = owid >> 1;                      // 8 rowgroups of 16
    const int och  = owid & 1;                       // 2 col halves of 64
    const int r0o  = org * 16;

    // ---- XCD self-identification, rank election, need-mask publication ----
    unsigned xcc_s;
    asm volatile("s_getreg_b32 %0, hwreg(HW_REG_XCC_ID)" : "=s"(xcc_s));
    const unsigned xcc = xcc_s & 7u;
    unsigned myneed;
    if (bid < 192) {
        myneed = 1u << layer;
        if (layer > 0) myneed |= 1u << (layer - 1);
    } else {
        myneed = 4u;                                  // out-proj reads h2
    }
    volatile unsigned* exu = (volatile unsigned*)&ex[0][0];
    if (threadIdx.x == 0) {
        exu[0] = __hip_atomic_fetch_add(&ticket[xcc], 1u, __ATOMIC_RELAXED,
                                        __HIP_MEMORY_SCOPE_AGENT);
        __hip_atomic_fetch_or(&needmask[xcc], myneed, __ATOMIC_RELAXED,
                              __HIP_MEMORY_SCOPE_AGENT);
    }
    __syncthreads();
    const unsigned rank = exu[0];
    unsigned barphase = 0;
    gridbar(bar, 194u * ++barphase);
    if (threadIdx.x == 0) {
        exu[0] = __hip_atomic_load(&ticket[xcc], __ATOMIC_RELAXED,
                                   __HIP_MEMORY_SCOPE_AGENT);
        exu[1] = __hip_atomic_load(&needmask[xcc], __ATOMIC_RELAXED,
                                   __HIP_MEMORY_SCOPE_AGENT);
    }
    __syncthreads();
    const unsigned nblk = exu[0];
    const unsigned mask = exu[1];
    const unsigned stbase = STAGE_BASE + xcc * STAGE_PER_XCD;

    for (int tick = 0; tick < 515; ++tick) {
        // ===== copy phase: fabric h -> XCD-local staging (needed layers) ===
        if (tick > 0) {
#pragma unroll
            for (int L = 0; L < 3; ++L) {
                if (!((mask >> L) & 1u)) continue;
                const int sw = tick - 1 - L;
                if (sw < 0 || sw >= T_) continue;
                const unsigned par = (unsigned)sw & 1u;
                const ushort_t* sh = wsU + OFF_HBH + ((unsigned)L * 2u + par) * 65536u;
                const ushort_t* sl = wsU + OFF_HBL + ((unsigned)L * 2u + par) * 65536u;
                ushort_t* dh = wsU + stbase + (unsigned)L * 131072u;
                ushort_t* dl = dh + 65536u;
                for (unsigned slx = rank * 512u + threadIdx.x; slx < 8192u;
                     slx += nblk * 512u) {
                    const unsigned off = slx * 8u;
                    uint4 vh, vl;
                    asm volatile("global_load_dwordx4 %0, %2, off sc0 sc1\n\t"
                                 "global_load_dwordx4 %1, %3, off sc0 sc1"
                                 : "=v"(vh), "=v"(vl) : "v"(sh + off), "v"(sl + off));
                    asm volatile("s_waitcnt vmcnt(0)" ::: "memory");
                    *(uint4*)(dh + off) = vh;
                    *(uint4*)(dl + off) = vl;
                }
            }
        }
        gridbar(bar, 194u * ++barphase);   // staging in own L2 (vmcnt(0) inside)

        // L1-only invalidate: staged lines may be stale in this CU's L1 from
        // last tick; L2 (weights + fresh staging) untouched.
        asm volatile("buffer_inv sc0" ::: "memory");

        // ================= compute phase ===================================
        if (bid < 192) {
            int s = tick - layer;
            if (s >= 0 && s < T_) {
                frag_cd acc[4][4] = {};

                if (w < 4) {
                    // ---- x-path K-quarter (layer0: noise K=128 -> kb = w)
                    if (layer == 0) {
                        const ushort_t* Bh = wsU + OFF_WXH;
                        const ushort_t* Bl = wsU + OFF_WXL;
                        int kb = w;
                        frag_ab ah[4], al[4];
#pragma unroll
                        for (int rt = 0; rt < 4; ++rt) {
                            const float* np = noise +
                                ((size_t)(r0 + rt * 16 + m) * T_ + s) * ND_ + kb * 32 + koff;
                            float4 f0 = *(const float4*)np;
                            float4 f1 = *(const float4*)(np + 4);
                            float xf[8] = {f0.x, f0.y, f0.z, f0.w, f1.x, f1.y, f1.z, f1.w};
#pragma unroll
                            for (int j = 0; j < 8; ++j) {
                                ushort_t hi = f2b(xf[j]);
                                ah[rt][j] = (short)hi;
                                al[rt][j] = (short)f2b(xf[j] - b2f(hi));
                            }
                        }
#pragma unroll
                        for (int q = 0; q < 4; ++q) {
                            size_t bo = ((size_t)(kb * 128 + q * 32 + cg) * 64 + lane) * 8;
                            frag_ab bh = *(const frag_ab*)(Bh + bo);
                            frag_ab bl = *(const frag_ab*)(Bl + bo);
#pragma unroll
                            for (int rt = 0; rt < 4; ++rt) {
                                acc[rt][q] = __builtin_amdgcn_mfma_f32_16x16x32_bf16(ah[rt], bh, acc[rt][q], 0, 0, 0);
                                acc[rt][q] = __builtin_amdgcn_mfma_f32_16x16x32_bf16(ah[rt], bl, acc[rt][q], 0, 0, 0);
                                acc[rt][q] = __builtin_amdgcn_mfma_f32_16x16x32_bf16(al[rt], bh, acc[rt][q], 0, 0, 0);
                            }
                        }
                    } else {
                        // A = staged h[layer-1] (fresh in own L2)
                        seg_accum64k(wsU + stbase + (unsigned)(layer - 1) * 131072u,
                                     wsU + stbase + (unsigned)(layer - 1) * 131072u + 65536u,
                                     wsU + OFF_WXH + 262144u + (size_t)(layer - 1) * 1048576,
                                     wsU + OFF_WXL + 262144u + (size_t)(layer - 1) * 1048576,
                                     r0, cg, w * 4, 4, acc);
                    }
                } else if (s > 0) {
                    // A = staged h[layer] (fresh in own L2)
                    seg_accum64k(wsU + stbase + (unsigned)layer * 131072u,
                                 wsU + stbase + (unsigned)layer * 131072u + 65536u,
                                 wsU + OFF_WHH + (size_t)layer * 1048576,
                                 wsU + OFF_WHL + (size_t)layer * 1048576,
                                 r0, cg, (w - 4) * 4, 4, acc);
                }

                // ---- write this wave's partial tile to LDS (static acc indices)
                {
                    float* eb = &ex[w][0];
#pragma unroll
                    for (int rt = 0; rt < 4; ++rt)
#pragma unroll
                        for (int q = 0; q < 4; ++q)
#pragma unroll
                            for (int reg = 0; reg < 4; ++reg)
                                eb[(rt * 16 + kq * 4 + reg) * 64 + q * 16 + m] = acc[rt][q][reg];
                }
                __syncthreads();

                // ---- combine 8 partials + epilogue: 2 elements/thread.
                // cterm: tiled layout, nt loads (no L2 allocate).
                const float* ctt = wsF + FOFF_CTERM +
                                   ((size_t)(layer * 32 + cg) * 128) * 64;
                float* cst = wsF + FOFF_C + layer * 65536;
                ushort_t* hhi = wsU + OFF_HBH + (layer * 2 + (s & 1)) * 65536;
                ushort_t* hlo = wsU + OFF_HBL + (layer * 2 + (s & 1)) * 65536;
                int tid = threadIdx.x;
#pragma unroll
                for (int ee = 0; ee < 2; ++ee) {
                    int e = tid + ee * 512;     // 0..1023
                    int row = e >> 4;           // 0..63 within tile
                    int hcol = e & 15;
                    int grow = r0 + row;
                    int hc = cg * 16 + hcol;
                    int rb = row * 64 + hcol;
                    // issue nt cterm loads first (fly under the LDS sums)
                    const float* cr = ctt + (size_t)grow * 64 + hcol;
                    float c0, c1, c2, c3;
                    asm volatile("global_load_dword %0, %4, off nt\n\t"
                                 "global_load_dword %1, %5, off nt\n\t"
                                 "global_load_dword %2, %6, off nt\n\t"
                                 "global_load_dword %3, %7, off nt"
                                 : "=v"(c0), "=v"(c1), "=v"(c2), "=v"(c3)
                                 : "v"(cr), "v"(cr + 16), "v"(cr + 32), "v"(cr + 48));
                    float gi = 0.0f, gf = 0.0f, gg = 0.0f, go = 0.0f;
#pragma unroll
                    for (int wv = 0; wv < 8; ++wv) {
                        gi += ex[wv][rb +  0];
                        gf += ex[wv][rb + 16];
                        gg += ex[wv][rb + 32];
                        go += ex[wv][rb + 48];
                    }
                    asm volatile("s_waitcnt vmcnt(0)" ::: "memory");
                    __builtin_amdgcn_sched_barrier(0);
                    gi += c0; gf += c1; gg += c2; go += c3;
                    float cp = (s > 0) ? cst[grow * H_ + hc] : 0.0f;
                    float cn = sig_(gf) * cp + sig_(gi) * tanh_(gg);
                    float hn = sig_(go) * tanh_(cn);
                    cst[grow * H_ + hc] = cn;
                    ushort_t hi = f2b(hn);
                    stg_short_sc(hhi + grow * H_ + hc, hi);
                    stg_short_sc(hlo + grow * H_ + hc, f2b(hn - b2f(hi)));
                    if (s == T_ - 1)   // h_fin, fp32, no bf16 quantization
                        out[8388608u + (size_t)layer * 65536 + grow * H_ + hc] = hn;
                }
            }
        } else {
            // ---- output projection: out[:, sp, :] = sigmoid(h2[sp] @ Wout + bout)
            int sp = tick - 3;
            if (sp >= 0 && sp < T_) {
                const ushort_t* A  = wsU + stbase + 2u * 131072u;   // staged h2 hi
                const ushort_t* Bw = wsU + OFF_WOUT;
                frag_cd acc2[4] = {};
#pragma unroll 2
                for (int kb = 0; kb < 16; ++kb) {
                    frag_ab a = *(const frag_ab*)(A + (size_t)(r0o + m) * H_ + kb * 32 + koff);
#pragma unroll
                    for (int cf = 0; cf < 4; ++cf) {
                        frag_ab b = *(const frag_ab*)(Bw + ((size_t)(kb * 8 + och * 4 + cf) * 64 + lane) * 8);
                        acc2[cf] = __builtin_amdgcn_mfma_f32_16x16x32_bf16(a, b, acc2[cf], 0, 0, 0);
                    }
                }
#pragma unroll
                for (int cf = 0; cf < 4; ++cf)
#pragma unroll
                    for (int reg = 0; reg < 4; ++reg) {
                        int row = r0o + kq * 4 + reg;
                        int oc = och * 64 + cf * 16 + m;
                        out[((size_t)row * T_ + sp) * LD_ + oc] =
                            sig_(acc2[cf][reg] + bout[oc]);
                    }
            }
        }

        gridbar(bar, 194u * ++barphase);   // tick boundary (vmcnt(0) inside)
    }
}

extern "C" void kernel_launch(void* const* d_in, const int* in_sizes, int n_in,
                              void* d_out, int out_size, void* d_ws, size_t ws_size,
                              hipStream_t stream) {
    const float* noise = (const float*)d_in[0];
    const float* hcpl  = (const float*)d_in[1];
    const float* Wx0   = (const float*)d_in[2];
    const float* Wxr   = (const float*)d_in[3];
    const float* Wh    = (const float*)d_in[4];
    const float* Wc    = (const float*)d_in[5];
    const float* bias  = (const float*)d_in[6];
    const float* Wout  = (const float*)d_in[7];
    const float* bout  = (const float*)d_in[8];
    float* out = (float*)d_out;
    char* ws = (char*)d_ws;
    ushort_t* wsU = (ushort_t*)ws;

    auto launch_swz = [&](const float* src, unsigned ohi, unsigned olo, int K, int N) {
        int total = (K / 32) * (N / 16) * 64;
        swz_kernel<<<(total + 255) / 256, 256, 0, stream>>>(src, wsU + ohi, wsU + olo, K, N);
    };
    for (int l = 0; l < 3; ++l)
        launch_swz(Wh + (size_t)l * H_ * G_, OFF_WHH + l * 1048576u, OFF_WHL + l * 1048576u, H_, G_);
    launch_swz(Wx0, OFF_WXH, OFF_WXL, ND_, G_);
    for (int l = 0; l < 2; ++l)
        launch_swz(Wxr + (size_t)l * H_ * G_, OFF_WXH + 262144u + l * 1048576u,
                   OFF_WXL + 262144u + l * 1048576u, H_, G_);
    for (int l = 0; l < 3; ++l)
        launch_swz(Wc + (size_t)l * H_ * G_, OFF_WCH + l * 1048576u, OFF_WCL + l * 1048576u, H_, G_);
    launch_swz(Wout, OFF_WOUT, OFF_SCR, H_, LD_);
    cvt_kernel<<<(3 * B_ * H_ + 255) / 256, 256, 0, stream>>>(hcpl, wsU + OFF_HCH, wsU + OFF_HCL,
                                                              3 * B_ * H_);
    cterm_kernel<<<192, 256, 0, stream>>>(ws, bias);

    // zero barrier counter + tickets + need-masks (stream-ordered after the
    // Wout swz that writes the scratch region; graph-capture-safe)
    hipMemsetAsync(ws + BAR_BYTE, 0, 128, stream);

    // ONE persistent cooperative kernel replaces the 515 tick launches.
    void* args[] = {(void*)&noise, (void*)&ws, (void*)&out, (void*)&bout};
    hipLaunchCooperativeKernel((void*)tick_persist, dim3(194), dim3(512), args, 0, stream);
}

// Round 7
// 10207.962 us; speedup vs baseline: 4.0722x; 1.2552x over previous
//
#include <hip/hip_runtime.h>
#include <hip/hip_bf16.h>

// ============================================================================
// BilateralGenerator: 3-layer coupled LSTM, B=128 T=512 H=512 ND=128 LD=128.
//
// Round 13 (last persistent round): r12 matched its FETCH prediction but not
// its time prediction -> tick is LATENCY/BARRIER-bound, not bytes-bound
// (24.9us/tick @ 14.7MB = 585 GB/s effective; MFMA only 1.7us). Fixes:
//  1. cterm -> 8 VGPRs/thread, loaded ONCE (tick-invariant!): kills 3MB/tick
//     nt-reads + the epilogue vmcnt(0) fabric stall.
//  2. c-state -> 2 VGPRs/thread (same thread owns the element every tick in
//     a persistent kernel): kills 1.5MB/tick + read latency. No memory c.
//  3. Two-level tree barrier: per-XCD arrival lines (64B apart) -> global
//     (<=8 arrivals) -> epoch broadcast. Monotonic phases, relaxed agent
//     atomics, vmcnt(0) drain before arrival (same semantics as the proven
//     flat barrier).
//  4. Copy phase: all sc1 loads issued into static regs, ONE vmcnt(0), then
//     all plain stores (1 fabric round instead of 2-3).
// Unchanged r12-proven: layer-clustered tile map, need-mask staging,
// XCC_ID election, buffer_inv sc0 per tick, split-precision hi/lo GEMMs.
// ============================================================================

typedef unsigned short ushort_t;

using frag_ab = __attribute__((ext_vector_type(8))) short;  // 8 bf16
using frag_cd = __attribute__((ext_vector_type(4))) float;  // 4 fp32

#define B_   128
#define T_   512
#define ND_  128
#define H_   512
#define G_   2048   // 4*H
#define LD_  128

// ---- workspace layout (ushort element offsets into bf16 region) ----
#define OFF_WHH   0u          // Wh hi: 3 x 512*2048
#define OFF_WHL   3145728u    // Wh lo
#define OFF_WXH   6291456u    // Wx hi: Wx0 (128*2048) then Wxr[0], Wxr[1]
#define OFF_WXL   8650752u    // Wx lo
#define OFF_WCH   11010048u   // Wc hi (DEAD after cterm -> staging)
#define OFF_WCL   14155776u   // Wc lo (dead after cterm)
#define OFF_WOUT  17301504u   // Wout hi: 512*128
#define OFF_HCH   17367040u   // h_coupled hi: 3 x 128*512
#define OFF_HCL   17563648u   // h_coupled lo
#define OFF_HBH   17760256u   // h buf hi: 3 layers x 2 parity x 128*512 (fabric)
#define OFF_HBL   18153472u   // h buf lo (fabric)
#define OFF_SCR   18546688u   // scratch (Wout lo dump) + barrier block
#define USH_BYTES 37224448u   // 18612224 ushorts * 2
#define BAR_BYTE  37093376u   // byte offset of barrier block (= OFF_SCR*2)
// per-XCD staging: 8 x [3 layers x (hi|lo) x 128*512] in the dead Wc region
#define STAGE_BASE    OFF_WCH
#define STAGE_PER_XCD 393216u  // 768 KB
// ---- fp32 region (float element offsets from USH_BYTES) ----
#define FOFF_C     0u         // (unused since r13: c lives in registers)
#define FOFF_CTERM 196608u    // Cterm TILED: [layer*32+cg][128 rows][64]

__device__ inline float sig_(float x)  { return 1.0f / (1.0f + __expf(-x)); }
__device__ inline float tanh_(float x) { return 2.0f / (1.0f + __expf(-2.0f * x)) - 1.0f; }

__device__ inline ushort_t f2b(float f) {
    __hip_bfloat16 h = __float2bfloat16(f);           // RNE
    return __builtin_bit_cast(unsigned short, h);
}
__device__ inline float b2f(ushort_t u) {
    unsigned int v = ((unsigned int)u) << 16;
    return __builtin_bit_cast(float, v);
}

// ---------------------------------------------------------------------------
// Weight swizzle + hi/lo split (round-2 verified).
// ---------------------------------------------------------------------------
__global__ void swz_kernel(const float* __restrict__ src,
                           ushort_t* __restrict__ dhi, ushort_t* __restrict__ dlo,
                           int K, int N) {
    int tid = blockIdx.x * 256 + threadIdx.x;
    int total = (K >> 5) * (N >> 4) * 64;
    if (tid >= total) return;
    int lane = tid & 63;
    int rest = tid >> 6;
    int NF = N >> 4;
    int nf = rest % NF;
    int kb = rest / NF;
    int kbase = kb * 32 + (lane >> 4) * 8;
    int n = nf * 16 + (lane & 15);
    union { ushort_t u[8]; uint4 v; } thi, tlo;
#pragma unroll
    for (int j = 0; j < 8; ++j) {
        float v = src[(size_t)(kbase + j) * N + n];
        ushort_t hi = f2b(v);
        thi.u[j] = hi;
        tlo.u[j] = f2b(v - b2f(hi));
    }
    *(uint4*)(dhi + (size_t)tid * 8) = thi.v;
    *(uint4*)(dlo + (size_t)tid * 8) = tlo.v;
}

__global__ void cvt_kernel(const float* __restrict__ src,
                           ushort_t* __restrict__ dhi, ushort_t* __restrict__ dlo, int n) {
    int i = blockIdx.x * 256 + threadIdx.x;
    if (i >= n) return;
    float v = src[i];
    ushort_t hi = f2b(v);
    dhi[i] = hi;
    dlo[i] = f2b(v - b2f(hi));
}

// ---------------------------------------------------------------------------
// Split-precision [16x64]-per-wave GEMM (round-2 verified) for cterm only.
// ---------------------------------------------------------------------------
__device__ inline void mfma_seg3(const ushort_t* __restrict__ Ah,
                                 const ushort_t* __restrict__ Al,
                                 const ushort_t* __restrict__ Bh,
                                 const ushort_t* __restrict__ Bl,
                                 int rowA, int cg, int nkb, frag_cd acc[4]) {
    int lane = threadIdx.x & 63;
    int koff = (lane >> 4) * 8;
#pragma unroll 2
    for (int kb = 0; kb < nkb; ++kb) {
        frag_ab ah = *(const frag_ab*)(Ah + (size_t)rowA * H_ + kb * 32 + koff);
        frag_ab al = *(const frag_ab*)(Al + (size_t)rowA * H_ + kb * 32 + koff);
#pragma unroll
        for (int q = 0; q < 4; ++q) {
            size_t bo = ((size_t)(kb * 128 + q * 32 + cg) * 64 + lane) * 8;
            frag_ab bh = *(const frag_ab*)(Bh + bo);
            frag_ab bl = *(const frag_ab*)(Bl + bo);
            acc[q] = __builtin_amdgcn_mfma_f32_16x16x32_bf16(ah, bh, acc[q], 0, 0, 0);
            acc[q] = __builtin_amdgcn_mfma_f32_16x16x32_bf16(ah, bl, acc[q], 0, 0, 0);
            acc[q] = __builtin_amdgcn_mfma_f32_16x16x32_bf16(al, bh, acc[q], 0, 0, 0);
        }
    }
}

// cterm written TILED: ct[(layer*32+cg)*128 + row][64] with 64 = q*16+m.
__global__ __launch_bounds__(256) void cterm_kernel(char* __restrict__ ws,
                                                    const float* __restrict__ bias) {
    ushort_t* wsU = (ushort_t*)ws;
    float* wsF = (float*)(ws + USH_BYTES);
    int lane = threadIdx.x & 63, w = threadIdx.x >> 6;
    int bid = blockIdx.x;
    int layer = bid >> 6;
    int sub = bid & 63;
    int rg = sub >> 5, cg = sub & 31;
    int m = lane & 15, kq = lane >> 4;
    int r0 = rg * 64 + w * 16;
    int rowA = r0 + m;
    frag_cd acc[4] = {};
    mfma_seg3(wsU + OFF_HCH + layer * 65536, wsU + OFF_HCL + layer * 65536,
              wsU + OFF_WCH + (size_t)layer * 1048576, wsU + OFF_WCL + (size_t)layer * 1048576,
              rowA, cg, 16, acc);
    float* ct = wsF + FOFF_CTERM + ((size_t)(layer * 32 + cg) * 128) * 64;
#pragma unroll
    for (int reg = 0; reg < 4; ++reg) {
        int row = r0 + kq * 4 + reg;
#pragma unroll
        for (int q = 0; q < 4; ++q) {
            int gcol = q * 512 + cg * 16 + m;
            ct[(size_t)row * 64 + q * 16 + m] = acc[q][reg] + bias[layer * G_ + gcol];
        }
    }
}

// ---------------------------------------------------------------------------
// Split-precision [64 rows x 64 gcols]-per-wave K-chunk segment (r7-proven,
// plain cached loads; A from XCD-local staging, fresh after buffer_inv sc0).
// ---------------------------------------------------------------------------
__device__ inline void seg_accum64k(const ushort_t* __restrict__ Ah,
                                    const ushort_t* __restrict__ Al,
                                    const ushort_t* __restrict__ Bh,
                                    const ushort_t* __restrict__ Bl,
                                    int r0, int cg, int kb0, int nkb, frag_cd acc[4][4]) {
    int lane = threadIdx.x & 63;
    int m = lane & 15;
    int koff = (lane >> 4) * 8;
#pragma unroll 2
    for (int kb = kb0; kb < kb0 + nkb; ++kb) {
        frag_ab ah[4], al[4];
#pragma unroll
        for (int rt = 0; rt < 4; ++rt) {
            size_t ao = (size_t)(r0 + rt * 16 + m) * H_ + kb * 32 + koff;
            ah[rt] = *(const frag_ab*)(Ah + ao);
            al[rt] = *(const frag_ab*)(Al + ao);
        }
#pragma unroll
        for (int q = 0; q < 4; ++q) {
            size_t bo = ((size_t)(kb * 128 + q * 32 + cg) * 64 + lane) * 8;
            frag_ab bh = *(const frag_ab*)(Bh + bo);
            frag_ab bl = *(const frag_ab*)(Bl + bo);
#pragma unroll
            for (int rt = 0; rt < 4; ++rt) {
                acc[rt][q] = __builtin_amdgcn_mfma_f32_16x16x32_bf16(ah[rt], bh, acc[rt][q], 0, 0, 0);
                acc[rt][q] = __builtin_amdgcn_mfma_f32_16x16x32_bf16(ah[rt], bl, acc[rt][q], 0, 0, 0);
                acc[rt][q] = __builtin_amdgcn_mfma_f32_16x16x32_bf16(al[rt], bh, acc[rt][q], 0, 0, 0);
            }
        }
    }
}

// 2-byte coherent store (h hi/lo) — write-through past the non-coherent L2.
__device__ inline void stg_short_sc(ushort_t* p, ushort_t v) {
    asm volatile("global_store_short %0, %1, off sc0 sc1"
                 :: "v"(p), "v"((unsigned)v) : "memory");
}

// ---------------------------------------------------------------------------
// Flat relaxed grid barrier (setup only; r11/r12-proven).
// ---------------------------------------------------------------------------
__device__ inline void gridbar(unsigned* bar, unsigned target) {
    asm volatile("s_waitcnt vmcnt(0)" ::: "memory");
    __syncthreads();
    if (threadIdx.x == 0) {
        __hip_atomic_fetch_add(bar, 1u, __ATOMIC_RELAXED, __HIP_MEMORY_SCOPE_AGENT);
        while (__hip_atomic_load(bar, __ATOMIC_RELAXED, __HIP_MEMORY_SCOPE_AGENT) < target)
            __builtin_amdgcn_s_sleep(1);
    }
    __syncthreads();
}

// ---------------------------------------------------------------------------
// Two-level tree barrier: per-XCD arrival counter (own 64B line) -> global
// counter (<=8 arrivals) -> epoch broadcast. Monotonic phases (1-based).
// Same drain/visibility semantics as the flat barrier.
// ---------------------------------------------------------------------------
__device__ inline void treebar(unsigned* arr, unsigned* garr, unsigned* epoch,
                               unsigned xcc, unsigned nblk, unsigned nxcd,
                               unsigned phase) {
    asm volatile("s_waitcnt vmcnt(0)" ::: "memory");
    __syncthreads();
    if (threadIdx.x == 0) {
        unsigned r = __hip_atomic_fetch_add(&arr[xcc * 16], 1u, __ATOMIC_RELAXED,
                                            __HIP_MEMORY_SCOPE_AGENT) + 1u;
        if (r == nblk * phase) {            // last block of this XCD this phase
            unsigned g = __hip_atomic_fetch_add(garr, 1u, __ATOMIC_RELAXED,
                                                __HIP_MEMORY_SCOPE_AGENT) + 1u;
            if (g == nxcd * phase)          // last XCD: publish epoch
                __hip_atomic_store(epoch, phase, __ATOMIC_RELAXED,
                                   __HIP_MEMORY_SCOPE_AGENT);
        }
        while (__hip_atomic_load(epoch, __ATOMIC_RELAXED,
                                 __HIP_MEMORY_SCOPE_AGENT) < phase)
            __builtin_amdgcn_s_sleep(1);
    }
    __syncthreads();
}

// ---------------------------------------------------------------------------
// Persistent pipeline: 194 blocks x 512 threads, 515 ticks, 2 tree barriers
// per tick. Tile map (layer-clustered): cb<192: x8=cb&7, j=cb>>3,
// p=x8*12+(j>>1), layer=p>>5, cg=p&31, rg64=j&1. Copy phase stages only
// layers in the per-XCD need-mask. bid 192/193: out-proj from staged h2.
// ---------------------------------------------------------------------------
__global__ __launch_bounds__(512, 2) void tick_persist(const float* __restrict__ noise,
                                                       char* __restrict__ ws,
                                                       float* __restrict__ out,
                                                       const float* __restrict__ bout) {
    __shared__ float ex[8][4096];   // 128 KB exactly

    ushort_t* wsU = (ushort_t*)ws;
    float* wsF = (float*)(ws + USH_BYTES);
    unsigned* bar      = (unsigned*)(ws + BAR_BYTE);          // setup flat bar
    unsigned* ticket   = (unsigned*)(ws + BAR_BYTE + 64);     // 8 x u32
    unsigned* needmask = (unsigned*)(ws + BAR_BYTE + 96);     // 8 x u32
    unsigned* garr     = (unsigned*)(ws + BAR_BYTE + 128);
    unsigned* epoch    = (unsigned*)(ws + BAR_BYTE + 192);
    unsigned* arr      = (unsigned*)(ws + BAR_BYTE + 256);    // stride 16 u32
    const int lane = threadIdx.x & 63;
    const int w = threadIdx.x >> 6;       // wave id 0..7
    const int bid = blockIdx.x;
    const int m = lane & 15, kq = lane >> 4;
    const int koff = kq * 8;

    // ---- tick-invariant block identity (layer-clustered map) ----
    const int cb   = (bid < 192) ? bid : 0;
    const int x8   = cb & 7, jj = cb >> 3;
    const int pp   = x8 * 12 + (jj >> 1);
    const int layer = pp >> 5;
    const int cg    = pp & 31;
    const int rg64  = jj & 1;
    const int r0    = rg64 * 64;
    const int owid = (bid - 192) * 8 + w;            // out-proj: 0..15
    const int org  = owid >> 1;                      // 8 rowgroups of 16
    const int och  = owid & 1;                       // 2 col halves of 64
    const int r0o  = org * 16;

    // ---- XCD self-identification, rank election, need-mask publication ----
    unsigned xcc_s;
    asm volatile("s_getreg_b32 %0, hwreg(HW_REG_XCC_ID)" : "=s"(xcc_s));
    const unsigned xcc = xcc_s & 7u;
    unsigned myneed;
    if (bid < 192) {
        myneed = 1u << layer;
        if (layer > 0) myneed |= 1u << (layer - 1);
    } else {
        myneed = 4u;                                  // out-proj reads h2
    }
    volatile unsigned* exu = (volatile unsigned*)&ex[0][0];
    if (threadIdx.x == 0) {
        exu[0] = __hip_atomic_fetch_add(&ticket[xcc], 1u, __ATOMIC_RELAXED,
                                        __HIP_MEMORY_SCOPE_AGENT);
        __hip_atomic_fetch_or(&needmask[xcc], myneed, __ATOMIC_RELAXED,
                              __HIP_MEMORY_SCOPE_AGENT);
    }
    __syncthreads();
    const unsigned rank = exu[0];
    gridbar(bar, 194u);
    if (threadIdx.x == 0) {
        exu[0] = __hip_atomic_load(&ticket[xcc], __ATOMIC_RELAXED,
                                   __HIP_MEMORY_SCOPE_AGENT);
        exu[1] = __hip_atomic_load(&needmask[xcc], __ATOMIC_RELAXED,
                                   __HIP_MEMORY_SCOPE_AGENT);
        unsigned nx = 0;
#pragma unroll
        for (int i = 0; i < 8; ++i)
            nx += (__hip_atomic_load(&ticket[i], __ATOMIC_RELAXED,
                                     __HIP_MEMORY_SCOPE_AGENT) != 0u) ? 1u : 0u;
        exu[2] = nx;
    }
    __syncthreads();
    const unsigned nblk = exu[0];
    const unsigned mask = exu[1];
    const unsigned nxcd = exu[2];
    const unsigned stbase = STAGE_BASE + xcc * STAGE_PER_XCD;

    // ---- tick-invariant per-thread state: cterm in regs, c in regs ----
    float ct_i[2], ct_f[2], ct_g[2], ct_o[2];
    float creg[2] = {0.0f, 0.0f};
    if (bid < 192) {
        const float* ctt = wsF + FOFF_CTERM + ((size_t)(layer * 32 + cg) * 128) * 64;
#pragma unroll
        for (int ee = 0; ee < 2; ++ee) {
            int e = (int)threadIdx.x + ee * 512;
            int row = e >> 4, hcol = e & 15;
            const float* cr = ctt + (size_t)(r0 + row) * 64 + hcol;
            ct_i[ee] = cr[0];  ct_f[ee] = cr[16];
            ct_g[ee] = cr[32]; ct_o[ee] = cr[48];
        }
    }

    for (int tick = 0; tick < 515; ++tick) {
        // ===== copy phase: fabric h -> XCD-local staging (single vm round) ==
        if (tick > 0) {
            int lay0 = -1, lay1 = -1, lay2 = -1;
            int nact = 0;
#pragma unroll
            for (int L = 0; L < 3; ++L) {
                if (!((mask >> L) & 1u)) continue;
                int sw = tick - 1 - L;
                if (sw < 0 || sw >= T_) continue;
                if (nact == 0) lay0 = L;
                else if (nact == 1) lay1 = L;
                else lay2 = L;
                ++nact;
            }
            const unsigned total  = (unsigned)nact * 8192u;
            const unsigned stride = nblk * 512u;
            const unsigned wi0 = rank * 512u + threadIdx.x;
            const unsigned wi1 = wi0 + stride;
            const unsigned wi2 = wi1 + stride;
            const bool f0 = wi0 < total, f1 = wi1 < total, f2 = wi2 < total;
            uint4 va0, vb0, va1, vb1, va2, vb2;
            unsigned d0 = 0, d1 = 0, d2 = 0;
#define CP_ADDR(WI, DST, PH, PL)                                               \
            {                                                                  \
                unsigned a_ = (WI) >> 13, sl_ = (WI) & 8191u;                  \
                int L_ = (a_ == 0u) ? lay0 : (a_ == 1u) ? lay1 : lay2;         \
                unsigned par_ = (unsigned)(tick - 1 - L_) & 1u;                \
                PH = wsU + OFF_HBH + ((unsigned)L_ * 2u + par_) * 65536u + sl_ * 8u; \
                PL = wsU + OFF_HBL + ((unsigned)L_ * 2u + par_) * 65536u + sl_ * 8u; \
                DST = (unsigned)L_ * 131072u + sl_ * 8u;                       \
            }
            if (f0) {
                const ushort_t *ph, *pl;
                CP_ADDR(wi0, d0, ph, pl);
                asm volatile("global_load_dwordx4 %0, %2, off sc0 sc1\n\t"
                             "global_load_dwordx4 %1, %3, off sc0 sc1"
                             : "=v"(va0), "=v"(vb0) : "v"(ph), "v"(pl));
            }
            if (f1) {
                const ushort_t *ph, *pl;
                CP_ADDR(wi1, d1, ph, pl);
                asm volatile("global_load_dwordx4 %0, %2, off sc0 sc1\n\t"
                             "global_load_dwordx4 %1, %3, off sc0 sc1"
                             : "=v"(va1), "=v"(vb1) : "v"(ph), "v"(pl));
            }
            if (f2) {
                const ushort_t *ph, *pl;
                CP_ADDR(wi2, d2, ph, pl);
                asm volatile("global_load_dwordx4 %0, %2, off sc0 sc1\n\t"
                             "global_load_dwordx4 %1, %3, off sc0 sc1"
                             : "=v"(va2), "=v"(vb2) : "v"(ph), "v"(pl));
            }
#undef CP_ADDR
            asm volatile("s_waitcnt vmcnt(0)" ::: "memory");
            __builtin_amdgcn_sched_barrier(0);
            if (f0) {
                *(uint4*)(wsU + stbase + d0) = va0;
                *(uint4*)(wsU + stbase + d0 + 65536u) = vb0;
            }
            if (f1) {
                *(uint4*)(wsU + stbase + d1) = va1;
                *(uint4*)(wsU + stbase + d1 + 65536u) = vb1;
            }
            if (f2) {
                *(uint4*)(wsU + stbase + d2) = va2;
                *(uint4*)(wsU + stbase + d2 + 65536u) = vb2;
            }
        }
        treebar(arr, garr, epoch, xcc, nblk, nxcd, (unsigned)tick * 2u + 1u);

        // L1-only invalidate: staged lines may be stale in this CU's L1 from
        // last tick; L2 (weights + fresh staging) untouched.
        asm volatile("buffer_inv sc0" ::: "memory");

        // ================= compute phase ===================================
        if (bid < 192) {
            int s = tick - layer;
            if (s >= 0 && s < T_) {
                frag_cd acc[4][4] = {};

                if (w < 4) {
                    // ---- x-path K-quarter (layer0: noise K=128 -> kb = w)
                    if (layer == 0) {
                        const ushort_t* Bh = wsU + OFF_WXH;
                        const ushort_t* Bl = wsU + OFF_WXL;
                        int kb = w;
                        frag_ab ah[4], al[4];
#pragma unroll
                        for (int rt = 0; rt < 4; ++rt) {
                            const float* np = noise +
                                ((size_t)(r0 + rt * 16 + m) * T_ + s) * ND_ + kb * 32 + koff;
                            float4 f0v = *(const float4*)np;
                            float4 f1v = *(const float4*)(np + 4);
                            float xf[8] = {f0v.x, f0v.y, f0v.z, f0v.w,
                                           f1v.x, f1v.y, f1v.z, f1v.w};
#pragma unroll
                            for (int j = 0; j < 8; ++j) {
                                ushort_t hi = f2b(xf[j]);
                                ah[rt][j] = (short)hi;
                                al[rt][j] = (short)f2b(xf[j] - b2f(hi));
                            }
                        }
#pragma unroll
                        for (int q = 0; q < 4; ++q) {
                            size_t bo = ((size_t)(kb * 128 + q * 32 + cg) * 64 + lane) * 8;
                            frag_ab bh = *(const frag_ab*)(Bh + bo);
                            frag_ab bl = *(const frag_ab*)(Bl + bo);
#pragma unroll
                            for (int rt = 0; rt < 4; ++rt) {
                                acc[rt][q] = __builtin_amdgcn_mfma_f32_16x16x32_bf16(ah[rt], bh, acc[rt][q], 0, 0, 0);
                                acc[rt][q] = __builtin_amdgcn_mfma_f32_16x16x32_bf16(ah[rt], bl, acc[rt][q], 0, 0, 0);
                                acc[rt][q] = __builtin_amdgcn_mfma_f32_16x16x32_bf16(al[rt], bh, acc[rt][q], 0, 0, 0);
                            }
                        }
                    } else {
                        // A = staged h[layer-1] (fresh in own L2)
                        seg_accum64k(wsU + stbase + (unsigned)(layer - 1) * 131072u,
                                     wsU + stbase + (unsigned)(layer - 1) * 131072u + 65536u,
                                     wsU + OFF_WXH + 262144u + (size_t)(layer - 1) * 1048576,
                                     wsU + OFF_WXL + 262144u + (size_t)(layer - 1) * 1048576,
                                     r0, cg, w * 4, 4, acc);
                    }
                } else if (s > 0) {
                    // A = staged h[layer] (fresh in own L2)
                    seg_accum64k(wsU + stbase + (unsigned)layer * 131072u,
                                 wsU + stbase + (unsigned)layer * 131072u + 65536u,
                                 wsU + OFF_WHH + (size_t)layer * 1048576,
                                 wsU + OFF_WHL + (size_t)layer * 1048576,
                                 r0, cg, (w - 4) * 4, 4, acc);
                }

                // ---- write this wave's partial tile to LDS (static acc indices)
                {
                    float* eb = &ex[w][0];
#pragma unroll
                    for (int rt = 0; rt < 4; ++rt)
#pragma unroll
                        for (int q = 0; q < 4; ++q)
#pragma unroll
                            for (int reg = 0; reg < 4; ++reg)
                                eb[(rt * 16 + kq * 4 + reg) * 64 + q * 16 + m] = acc[rt][q][reg];
                }
                __syncthreads();

                // ---- combine 8 partials + epilogue: 2 elements/thread.
                // cterm and c are in registers (tick-invariant / thread-owned).
                ushort_t* hhi = wsU + OFF_HBH + (layer * 2 + (s & 1)) * 65536;
                ushort_t* hlo = wsU + OFF_HBL + (layer * 2 + (s & 1)) * 65536;
                int tid = threadIdx.x;
#pragma unroll
                for (int ee = 0; ee < 2; ++ee) {
                    int e = tid + ee * 512;     // 0..1023
                    int row = e >> 4;           // 0..63 within tile
                    int hcol = e & 15;
                    int grow = r0 + row;
                    int hc = cg * 16 + hcol;
                    int rb = row * 64 + hcol;
                    float gi = 0.0f, gf = 0.0f, gg = 0.0f, go = 0.0f;
#pragma unroll
                    for (int wv = 0; wv < 8; ++wv) {
                        gi += ex[wv][rb +  0];
                        gf += ex[wv][rb + 16];
                        gg += ex[wv][rb + 32];
                        go += ex[wv][rb + 48];
                    }
                    gi += ct_i[ee]; gf += ct_f[ee];
                    gg += ct_g[ee]; go += ct_o[ee];
                    float cp = (s > 0) ? creg[ee] : 0.0f;
                    float cn = sig_(gf) * cp + sig_(gi) * tanh_(gg);
                    float hn = sig_(go) * tanh_(cn);
                    creg[ee] = cn;
                    ushort_t hi = f2b(hn);
                    stg_short_sc(hhi + grow * H_ + hc, hi);
                    stg_short_sc(hlo + grow * H_ + hc, f2b(hn - b2f(hi)));
                    if (s == T_ - 1)   // h_fin, fp32, no bf16 quantization
                        out[8388608u + (size_t)layer * 65536 + grow * H_ + hc] = hn;
                }
            }
        } else {
            // ---- output projection: out[:, sp, :] = sigmoid(h2[sp] @ Wout + bout)
            int sp = tick - 3;
            if (sp >= 0 && sp < T_) {
                const ushort_t* A  = wsU + stbase + 2u * 131072u;   // staged h2 hi
                const ushort_t* Bw = wsU + OFF_WOUT;
                frag_cd acc2[4] = {};
#pragma unroll 2
                for (int kb = 0; kb < 16; ++kb) {
                    frag_ab a = *(const frag_ab*)(A + (size_t)(r0o + m) * H_ + kb * 32 + koff);
#pragma unroll
                    for (int cf = 0; cf < 4; ++cf) {
                        frag_ab b = *(const frag_ab*)(Bw + ((size_t)(kb * 8 + och * 4 + cf) * 64 + lane) * 8);
                        acc2[cf] = __builtin_amdgcn_mfma_f32_16x16x32_bf16(a, b, acc2[cf], 0, 0, 0);
                    }
                }
#pragma unroll
                for (int cf = 0; cf < 4; ++cf)
#pragma unroll
                    for (int reg = 0; reg < 4; ++reg) {
                        int row = r0o + kq * 4 + reg;
                        int oc = och * 64 + cf * 16 + m;
                        out[((size_t)row * T_ + sp) * LD_ + oc] =
                            sig_(acc2[cf][reg] + bout[oc]);
                    }
            }
        }

        treebar(arr, garr, epoch, xcc, nblk, nxcd, (unsigned)tick * 2u + 2u);
    }
}

extern "C" void kernel_launch(void* const* d_in, const int* in_sizes, int n_in,
                              void* d_out, int out_size, void* d_ws, size_t ws_size,
                              hipStream_t stream) {
    const float* noise = (const float*)d_in[0];
    const float* hcpl  = (const float*)d_in[1];
    const float* Wx0   = (const float*)d_in[2];
    const float* Wxr   = (const float*)d_in[3];
    const float* Wh    = (const float*)d_in[4];
    const float* Wc    = (const float*)d_in[5];
    const float* bias  = (const float*)d_in[6];
    const float* Wout  = (const float*)d_in[7];
    const float* bout  = (const float*)d_in[8];
    float* out = (float*)d_out;
    char* ws = (char*)d_ws;
    ushort_t* wsU = (ushort_t*)ws;

    auto launch_swz = [&](const float* src, unsigned ohi, unsigned olo, int K, int N) {
        int total = (K / 32) * (N / 16) * 64;
        swz_kernel<<<(total + 255) / 256, 256, 0, stream>>>(src, wsU + ohi, wsU + olo, K, N);
    };
    for (int l = 0; l < 3; ++l)
        launch_swz(Wh + (size_t)l * H_ * G_, OFF_WHH + l * 1048576u, OFF_WHL + l * 1048576u, H_, G_);
    launch_swz(Wx0, OFF_WXH, OFF_WXL, ND_, G_);
    for (int l = 0; l < 2; ++l)
        launch_swz(Wxr + (size_t)l * H_ * G_, OFF_WXH + 262144u + l * 1048576u,
                   OFF_WXL + 262144u + l * 1048576u, H_, G_);
    for (int l = 0; l < 3; ++l)
        launch_swz(Wc + (size_t)l * H_ * G_, OFF_WCH + l * 1048576u, OFF_WCL + l * 1048576u, H_, G_);
    launch_swz(Wout, OFF_WOUT, OFF_SCR, H_, LD_);
    cvt_kernel<<<(3 * B_ * H_ + 255) / 256, 256, 0, stream>>>(hcpl, wsU + OFF_HCH, wsU + OFF_HCL,
                                                              3 * B_ * H_);
    cterm_kernel<<<192, 256, 0, stream>>>(ws, bias);

    // zero barrier block: flat bar, tickets, need-masks, garr, epoch, arr[]
    // (stream-ordered after the Wout swz that writes the scratch region)
    hipMemsetAsync(ws + BAR_BYTE, 0, 1024, stream);

    // ONE persistent cooperative kernel replaces the 515 tick launches.
    void* args[] = {(void*)&noise, (void*)&ws, (void*)&out, (void*)&bout};
    hipLaunchCooperativeKernel((void*)tick_persist, dim3(194), dim3(512), args, 0, stream);
}

// Round 8
// 7770.429 us; speedup vs baseline: 5.3496x; 1.3137x over previous
//
#include <hip/hip_runtime.h>
#include <hip/hip_bf16.h>

// ============================================================================
// BilateralGenerator: 3-layer coupled LSTM, B=128 T=512 H=512 ND=128 LD=128.
//
// Round 14: persistent arc closed per pre-commitment (r13 10.2ms > r7 7.75ms;
// six rounds established the ~1.2-1.4 TB/s L2-miss service-rate constant and
// a ~10us/tick persistent floor). REVERT to the r7 multi-launch keeper and
// remove its measured byte-waste using the r12/r13 refcheck-verified layouts:
//  - cterm TILED [(layer*32+cg)][128][64] (gates packed in the 64-col dim):
//    full 128B-line utilization; was 4 floats @ stride 512 = 50% waste.
//    6 -> 3 MB/tick.
//  - c-state TILED per block [(layer*32+cg)*2+rg][64x16] dense: read+write
//    both full-line. 3+3 -> 1.5+1.5 MB/tick.
//  - Everything else byte-identical to r7 (515 launches, 194 blocks x 512
//    thr, 8 waves = x/h K-quarters, 128KB LDS partial exchange, plain
//    cached loads/stores — dispatch-boundary invalidation provides
//    cross-tick visibility).
// Math identical to r2..r13 (split-precision bf16 hi/lo GEMMs).
// ============================================================================

typedef unsigned short ushort_t;

using frag_ab = __attribute__((ext_vector_type(8))) short;  // 8 bf16
using frag_cd = __attribute__((ext_vector_type(4))) float;  // 4 fp32

#define B_   128
#define T_   512
#define ND_  128
#define H_   512
#define G_   2048   // 4*H
#define LD_  128

// ---- workspace layout (ushort element offsets into bf16 region) ----
#define OFF_WHH   0u          // Wh hi: 3 x 512*2048
#define OFF_WHL   3145728u    // Wh lo
#define OFF_WXH   6291456u    // Wx hi: Wx0 (128*2048) then Wxr[0], Wxr[1]
#define OFF_WXL   8650752u    // Wx lo
#define OFF_WCH   11010048u   // Wc hi: 3 x 512*2048
#define OFF_WCL   14155776u   // Wc lo
#define OFF_WOUT  17301504u   // Wout hi: 512*128
#define OFF_HCH   17367040u   // h_coupled hi: 3 x 128*512
#define OFF_HCL   17563648u   // h_coupled lo
#define OFF_HBH   17760256u   // h buf hi: 3 layers x 2 parity x 128*512
#define OFF_HBL   18153472u   // h buf lo
#define OFF_SCR   18546688u   // scratch (Wout lo, unused): 65536
#define USH_BYTES 37224448u   // 18612224 ushorts * 2
// ---- fp32 region (float element offsets from USH_BYTES) ----
#define FOFF_C     0u         // c state TILED: [(layer*32+cg)*2+rg][64*16]
#define FOFF_CTERM 196608u    // Cterm TILED: [(layer*32+cg)][128][64]

__device__ inline float sig_(float x)  { return 1.0f / (1.0f + __expf(-x)); }
__device__ inline float tanh_(float x) { return 2.0f / (1.0f + __expf(-2.0f * x)) - 1.0f; }

__device__ inline ushort_t f2b(float f) {
    __hip_bfloat16 h = __float2bfloat16(f);           // RNE
    return __builtin_bit_cast(unsigned short, h);
}
__device__ inline float b2f(ushort_t u) {
    unsigned int v = ((unsigned int)u) << 16;
    return __builtin_bit_cast(float, v);
}

// ---------------------------------------------------------------------------
// Weight swizzle + hi/lo split (round-2 verified).
// ---------------------------------------------------------------------------
__global__ void swz_kernel(const float* __restrict__ src,
                           ushort_t* __restrict__ dhi, ushort_t* __restrict__ dlo,
                           int K, int N) {
    int tid = blockIdx.x * 256 + threadIdx.x;
    int total = (K >> 5) * (N >> 4) * 64;
    if (tid >= total) return;
    int lane = tid & 63;
    int rest = tid >> 6;
    int NF = N >> 4;
    int nf = rest % NF;
    int kb = rest / NF;
    int kbase = kb * 32 + (lane >> 4) * 8;
    int n = nf * 16 + (lane & 15);
    union { ushort_t u[8]; uint4 v; } thi, tlo;
#pragma unroll
    for (int j = 0; j < 8; ++j) {
        float v = src[(size_t)(kbase + j) * N + n];
        ushort_t hi = f2b(v);
        thi.u[j] = hi;
        tlo.u[j] = f2b(v - b2f(hi));
    }
    *(uint4*)(dhi + (size_t)tid * 8) = thi.v;
    *(uint4*)(dlo + (size_t)tid * 8) = tlo.v;
}

__global__ void cvt_kernel(const float* __restrict__ src,
                           ushort_t* __restrict__ dhi, ushort_t* __restrict__ dlo, int n) {
    int i = blockIdx.x * 256 + threadIdx.x;
    if (i >= n) return;
    float v = src[i];
    ushort_t hi = f2b(v);
    dhi[i] = hi;
    dlo[i] = f2b(v - b2f(hi));
}

// ---------------------------------------------------------------------------
// Split-precision [16x64]-per-wave GEMM (round-2 verified) for cterm only.
// ---------------------------------------------------------------------------
__device__ inline void mfma_seg3(const ushort_t* __restrict__ Ah,
                                 const ushort_t* __restrict__ Al,
                                 const ushort_t* __restrict__ Bh,
                                 const ushort_t* __restrict__ Bl,
                                 int rowA, int cg, int nkb, frag_cd acc[4]) {
    int lane = threadIdx.x & 63;
    int koff = (lane >> 4) * 8;
#pragma unroll 2
    for (int kb = 0; kb < nkb; ++kb) {
        frag_ab ah = *(const frag_ab*)(Ah + (size_t)rowA * H_ + kb * 32 + koff);
        frag_ab al = *(const frag_ab*)(Al + (size_t)rowA * H_ + kb * 32 + koff);
#pragma unroll
        for (int q = 0; q < 4; ++q) {
            size_t bo = ((size_t)(kb * 128 + q * 32 + cg) * 64 + lane) * 8;
            frag_ab bh = *(const frag_ab*)(Bh + bo);
            frag_ab bl = *(const frag_ab*)(Bl + bo);
            acc[q] = __builtin_amdgcn_mfma_f32_16x16x32_bf16(ah, bh, acc[q], 0, 0, 0);
            acc[q] = __builtin_amdgcn_mfma_f32_16x16x32_bf16(ah, bl, acc[q], 0, 0, 0);
            acc[q] = __builtin_amdgcn_mfma_f32_16x16x32_bf16(al, bh, acc[q], 0, 0, 0);
        }
    }
}

// cterm written TILED: ct[((layer*32+cg)*128 + row)*64 + q*16 + m]
// (r12/r13 refcheck-verified layout; full-line epilogue reads).
__global__ __launch_bounds__(256) void cterm_kernel(char* __restrict__ ws,
                                                    const float* __restrict__ bias) {
    ushort_t* wsU = (ushort_t*)ws;
    float* wsF = (float*)(ws + USH_BYTES);
    int lane = threadIdx.x & 63, w = threadIdx.x >> 6;
    int bid = blockIdx.x;
    int layer = bid >> 6;
    int sub = bid & 63;
    int rg = sub >> 5, cg = sub & 31;
    int m = lane & 15, kq = lane >> 4;
    int r0 = rg * 64 + w * 16;
    int rowA = r0 + m;
    frag_cd acc[4] = {};
    mfma_seg3(wsU + OFF_HCH + layer * 65536, wsU + OFF_HCL + layer * 65536,
              wsU + OFF_WCH + (size_t)layer * 1048576, wsU + OFF_WCL + (size_t)layer * 1048576,
              rowA, cg, 16, acc);
    float* ct = wsF + FOFF_CTERM + ((size_t)(layer * 32 + cg) * 128) * 64;
#pragma unroll
    for (int reg = 0; reg < 4; ++reg) {
        int row = r0 + kq * 4 + reg;
#pragma unroll
        for (int q = 0; q < 4; ++q) {
            int gcol = q * 512 + cg * 16 + m;
            ct[(size_t)row * 64 + q * 16 + m] = acc[q][reg] + bias[layer * G_ + gcol];
        }
    }
}

// ---------------------------------------------------------------------------
// Split-precision [64 rows x 64 gcols]-per-wave K-chunk segment: 4 rowtiles,
// B frags reused 4x from registers, kb in [kb0, kb0+nkb). Static reg indices.
// ---------------------------------------------------------------------------
__device__ inline void seg_accum64k(const ushort_t* __restrict__ Ah,
                                    const ushort_t* __restrict__ Al,
                                    const ushort_t* __restrict__ Bh,
                                    const ushort_t* __restrict__ Bl,
                                    int r0, int cg, int kb0, int nkb, frag_cd acc[4][4]) {
    int lane = threadIdx.x & 63;
    int m = lane & 15;
    int koff = (lane >> 4) * 8;
#pragma unroll 2
    for (int kb = kb0; kb < kb0 + nkb; ++kb) {
        frag_ab ah[4], al[4];
#pragma unroll
        for (int rt = 0; rt < 4; ++rt) {
            size_t ao = (size_t)(r0 + rt * 16 + m) * H_ + kb * 32 + koff;
            ah[rt] = *(const frag_ab*)(Ah + ao);
            al[rt] = *(const frag_ab*)(Al + ao);
        }
#pragma unroll
        for (int q = 0; q < 4; ++q) {
            size_t bo = ((size_t)(kb * 128 + q * 32 + cg) * 64 + lane) * 8;
            frag_ab bh = *(const frag_ab*)(Bh + bo);
            frag_ab bl = *(const frag_ab*)(Bl + bo);
#pragma unroll
            for (int rt = 0; rt < 4; ++rt) {
                acc[rt][q] = __builtin_amdgcn_mfma_f32_16x16x32_bf16(ah[rt], bh, acc[rt][q], 0, 0, 0);
                acc[rt][q] = __builtin_amdgcn_mfma_f32_16x16x32_bf16(ah[rt], bl, acc[rt][q], 0, 0, 0);
                acc[rt][q] = __builtin_amdgcn_mfma_f32_16x16x32_bf16(al[rt], bh, acc[rt][q], 0, 0, 0);
            }
        }
    }
}

// ---------------------------------------------------------------------------
// One pipeline tick: 194 blocks x 512 threads (8 waves).
// bid < 192: cell blocks, bid = rg64*96 + (layer*32 + cg). Block computes the
//   [64r x 64gc] tile: waves 0-3 = x-path K quarters, waves 4-7 = h-path K
//   quarters; 8-way LDS partial-sum (128 KB) + fused epilogue with TILED
//   cterm reads and TILED c-state read/write (full-line utilization).
// bid 192/193: out-proj, 8 waves each = (16-row group, col-half).
// ---------------------------------------------------------------------------
__global__ __launch_bounds__(512, 2) void tick_kernel(const float* __restrict__ noise,
                                                      char* __restrict__ ws,
                                                      float* __restrict__ out,
                                                      const float* __restrict__ bout,
                                                      int tick) {
    __shared__ float ex[8][4096];   // 128 KB: per-wave [64r x 64gc] partials

    ushort_t* wsU = (ushort_t*)ws;
    float* wsF = (float*)(ws + USH_BYTES);
    int lane = threadIdx.x & 63;
    int w = threadIdx.x >> 6;       // wave id 0..7
    int bid = blockIdx.x;
    int m = lane & 15, kq = lane >> 4;
    int koff = kq * 8;

    if (bid < 192) {
        int rg64 = bid / 96;        // 0..1: 64-row group
        int u = bid % 96;           // XCD = u % 8 (both rowgroups same XCD)
        int layer = u >> 5;
        int cg = u & 31;
        int s = tick - layer;
        if (s < 0 || s >= T_) return;
        int r0 = rg64 * 64;
        frag_cd acc[4][4] = {};

        if (w < 4) {
            // ---- x-path K-quarter (layer0: noise K=128 -> kb = w)
            if (layer == 0) {
                const ushort_t* Bh = wsU + OFF_WXH;
                const ushort_t* Bl = wsU + OFF_WXL;
                int kb = w;
                frag_ab ah[4], al[4];
#pragma unroll
                for (int rt = 0; rt < 4; ++rt) {
                    const float* np = noise +
                        ((size_t)(r0 + rt * 16 + m) * T_ + s) * ND_ + kb * 32 + koff;
                    float4 f0 = *(const float4*)np;
                    float4 f1 = *(const float4*)(np + 4);
                    float xf[8] = {f0.x, f0.y, f0.z, f0.w, f1.x, f1.y, f1.z, f1.w};
#pragma unroll
                    for (int j = 0; j < 8; ++j) {
                        ushort_t hi = f2b(xf[j]);
                        ah[rt][j] = (short)hi;
                        al[rt][j] = (short)f2b(xf[j] - b2f(hi));
                    }
                }
#pragma unroll
                for (int q = 0; q < 4; ++q) {
                    size_t bo = ((size_t)(kb * 128 + q * 32 + cg) * 64 + lane) * 8;
                    frag_ab bh = *(const frag_ab*)(Bh + bo);
                    frag_ab bl = *(const frag_ab*)(Bl + bo);
#pragma unroll
                    for (int rt = 0; rt < 4; ++rt) {
                        acc[rt][q] = __builtin_amdgcn_mfma_f32_16x16x32_bf16(ah[rt], bh, acc[rt][q], 0, 0, 0);
                        acc[rt][q] = __builtin_amdgcn_mfma_f32_16x16x32_bf16(ah[rt], bl, acc[rt][q], 0, 0, 0);
                        acc[rt][q] = __builtin_amdgcn_mfma_f32_16x16x32_bf16(al[rt], bh, acc[rt][q], 0, 0, 0);
                    }
                }
            } else {
                unsigned hb = (unsigned)((layer - 1) * 2 + (s & 1)) * 65536u;
                seg_accum64k(wsU + OFF_HBH + hb, wsU + OFF_HBL + hb,
                             wsU + OFF_WXH + 262144u + (size_t)(layer - 1) * 1048576,
                             wsU + OFF_WXL + 262144u + (size_t)(layer - 1) * 1048576,
                             r0, cg, w * 4, 4, acc);
            }
        } else if (s > 0) {
            // ---- h-path K-quarter (skip at s==0)
            unsigned hb = (unsigned)(layer * 2 + ((s - 1) & 1)) * 65536u;
            seg_accum64k(wsU + OFF_HBH + hb, wsU + OFF_HBL + hb,
                         wsU + OFF_WHH + (size_t)layer * 1048576,
                         wsU + OFF_WHL + (size_t)layer * 1048576,
                         r0, cg, (w - 4) * 4, 4, acc);
        }

        // ---- write this wave's partial tile to LDS (static acc indices)
        {
            float* eb = &ex[w][0];
#pragma unroll
            for (int rt = 0; rt < 4; ++rt)
#pragma unroll
                for (int q = 0; q < 4; ++q)
#pragma unroll
                    for (int reg = 0; reg < 4; ++reg)
                        eb[(rt * 16 + kq * 4 + reg) * 64 + q * 16 + m] = acc[rt][q][reg];
        }
        __syncthreads();

        // ---- combine 8 partials + activation epilogue: 2 elements/thread.
        // cterm TILED (full-line reads); c TILED per block (full-line r/w).
        const float* ctt = wsF + FOFF_CTERM + ((size_t)(layer * 32 + cg) * 128) * 64;
        float* cst = wsF + FOFF_C + ((size_t)((layer * 32 + cg) * 2 + rg64)) * 1024;
        ushort_t* hhi = wsU + OFF_HBH + (layer * 2 + (s & 1)) * 65536;
        ushort_t* hlo = wsU + OFF_HBL + (layer * 2 + (s & 1)) * 65536;
        int tid = threadIdx.x;
#pragma unroll
        for (int ee = 0; ee < 2; ++ee) {
            int e = tid + ee * 512;     // 0..1023
            int row = e >> 4;           // 0..63 within tile
            int hcol = e & 15;
            int grow = r0 + row;
            int hc = cg * 16 + hcol;
            int rb = row * 64 + hcol;
            float gi = 0.0f, gf = 0.0f, gg = 0.0f, go = 0.0f;
#pragma unroll
            for (int wv = 0; wv < 8; ++wv) {
                gi += ex[wv][rb +  0];
                gf += ex[wv][rb + 16];
                gg += ex[wv][rb + 32];
                go += ex[wv][rb + 48];
            }
            const float* cr = ctt + (size_t)grow * 64 + hcol;
            gi += cr[0]; gf += cr[16]; gg += cr[32]; go += cr[48];
            float cp = (s > 0) ? cst[row * 16 + hcol] : 0.0f;
            float cn = sig_(gf) * cp + sig_(gi) * tanh_(gg);
            float hn = sig_(go) * tanh_(cn);
            cst[row * 16 + hcol] = cn;
            ushort_t hi = f2b(hn);
            hhi[grow * H_ + hc] = hi;
            hlo[grow * H_ + hc] = f2b(hn - b2f(hi));
            if (s == T_ - 1)   // h_fin, fp32, no bf16 quantization
                out[8388608u + (size_t)layer * 65536 + grow * H_ + hc] = hn;
        }
    } else {
        // ---- output projection: out[:, sp, :] = sigmoid(h2[sp] @ Wout + bout)
        int sp = tick - 3;
        if (sp < 0 || sp >= T_) return;
        int owid = (bid - 192) * 8 + w;  // 0..15
        int rg = owid >> 1;              // 8 rowgroups of 16
        int ch = owid & 1;               // 2 col halves of 64
        int r0o = rg * 16;
        const ushort_t* A  = wsU + OFF_HBH + (4 + (sp & 1)) * 65536;
        const ushort_t* Bw = wsU + OFF_WOUT;
        frag_cd acc2[4] = {};
#pragma unroll 2
        for (int kb = 0; kb < 16; ++kb) {
            frag_ab a = *(const frag_ab*)(A + (size_t)(r0o + m) * H_ + kb * 32 + koff);
#pragma unroll
            for (int cf = 0; cf < 4; ++cf) {
                frag_ab b = *(const frag_ab*)(Bw + ((size_t)(kb * 8 + ch * 4 + cf) * 64 + lane) * 8);
                acc2[cf] = __builtin_amdgcn_mfma_f32_16x16x32_bf16(a, b, acc2[cf], 0, 0, 0);
            }
        }
#pragma unroll
        for (int cf = 0; cf < 4; ++cf)
#pragma unroll
            for (int reg = 0; reg < 4; ++reg) {
                int row = r0o + kq * 4 + reg;
                int oc = ch * 64 + cf * 16 + m;
                out[((size_t)row * T_ + sp) * LD_ + oc] =
                    sig_(acc2[cf][reg] + bout[oc]);
            }
    }
}

extern "C" void kernel_launch(void* const* d_in, const int* in_sizes, int n_in,
                              void* d_out, int out_size, void* d_ws, size_t ws_size,
                              hipStream_t stream) {
    const float* noise = (const float*)d_in[0];
    const float* hcpl  = (const float*)d_in[1];
    const float* Wx0   = (const float*)d_in[2];
    const float* Wxr   = (const float*)d_in[3];
    const float* Wh    = (const float*)d_in[4];
    const float* Wc    = (const float*)d_in[5];
    const float* bias  = (const float*)d_in[6];
    const float* Wout  = (const float*)d_in[7];
    const float* bout  = (const float*)d_in[8];
    float* out = (float*)d_out;
    char* ws = (char*)d_ws;
    ushort_t* wsU = (ushort_t*)ws;

    auto launch_swz = [&](const float* src, unsigned ohi, unsigned olo, int K, int N) {
        int total = (K / 32) * (N / 16) * 64;
        swz_kernel<<<(total + 255) / 256, 256, 0, stream>>>(src, wsU + ohi, wsU + olo, K, N);
    };
    for (int l = 0; l < 3; ++l)
        launch_swz(Wh + (size_t)l * H_ * G_, OFF_WHH + l * 1048576u, OFF_WHL + l * 1048576u, H_, G_);
    launch_swz(Wx0, OFF_WXH, OFF_WXL, ND_, G_);
    for (int l = 0; l < 2; ++l)
        launch_swz(Wxr + (size_t)l * H_ * G_, OFF_WXH + 262144u + l * 1048576u,
                   OFF_WXL + 262144u + l * 1048576u, H_, G_);
    for (int l = 0; l < 3; ++l)
        launch_swz(Wc + (size_t)l * H_ * G_, OFF_WCH + l * 1048576u, OFF_WCL + l * 1048576u, H_, G_);
    launch_swz(Wout, OFF_WOUT, OFF_SCR, H_, LD_);
    cvt_kernel<<<(3 * B_ * H_ + 255) / 256, 256, 0, stream>>>(hcpl, wsU + OFF_HCH, wsU + OFF_HCL,
                                                              3 * B_ * H_);
    cterm_kernel<<<192, 256, 0, stream>>>(ws, bias);

    // 515 ticks: layer l covers steps at ticks [l, l+511]; out-proj at [3, 514]
    for (int t = 0; t < 515; ++t)
        tick_kernel<<<194, 512, 0, stream>>>(noise, ws, out, bout, t);
}